// Round 1
// baseline (735.377 us; speedup 1.0000x reference)
//
#include <hip/hip_runtime.h>
#include <hip/hip_bf16.h>
#include <stdint.h>

#define NN 100000
#define NE 1600000
#define DF 128
#define DH 256
#define NC 40
#define NCHUNK 782   // ceil(NN/128)

typedef __attribute__((ext_vector_type(8))) short short8;
typedef __attribute__((ext_vector_type(4))) float f32x4;

typedef const __attribute__((address_space(1))) unsigned int* gas1;
typedef __attribute__((address_space(3))) unsigned int* las3;

__device__ __forceinline__ void gload16(const void* g, void* l) {
  __builtin_amdgcn_global_load_lds((gas1)g, (las3)l, 16, 0, 0);
}

__device__ __forceinline__ unsigned short f2bf(float f) {
  union { float f; unsigned u; } v; v.f = f;
  unsigned r = v.u + 0x7FFFu + ((v.u >> 16) & 1u);
  return (unsigned short)(r >> 16);
}

// ---------------- CSR build ----------------
__global__ void k_hist(const int* __restrict__ dst, int* __restrict__ cnt) {
  int i = blockIdx.x * blockDim.x + threadIdx.x;
  if (i < NE) atomicAdd(&cnt[dst[i]], 1);
}

__global__ void k_scanA(const int* __restrict__ cnt, int* __restrict__ chunk_off) {
  __shared__ int part[800];
  int tid = threadIdx.x;
  if (tid < NCHUNK) {
    int s = 0, base = tid * 128;
    for (int j = 0; j < 128; ++j) { int idx = base + j; if (idx < NN) s += cnt[idx]; }
    part[tid] = s;
  }
  __syncthreads();
  if (tid == 0) {
    int run = 0;
    for (int i = 0; i < NCHUNK; ++i) { int t = part[i]; part[i] = run; run += t; }
  }
  __syncthreads();
  if (tid < NCHUNK) chunk_off[tid] = part[tid];
}

__global__ void k_scanB(const int* __restrict__ cnt, const int* __restrict__ chunk_off,
                        int* __restrict__ row_ptr, int* __restrict__ cursor) {
  __shared__ int s[128];
  int tid = threadIdx.x;
  int n = blockIdx.x * 128 + tid;
  int v = (n < NN) ? cnt[n] : 0;
  s[tid] = v;
  __syncthreads();
  for (int off = 1; off < 128; off <<= 1) {
    int add = (tid >= off) ? s[tid - off] : 0;
    __syncthreads();
    s[tid] += add;
    __syncthreads();
  }
  int incl = s[tid];
  int excl = incl - v;
  int rp = chunk_off[blockIdx.x] + excl;
  if (n < NN) {
    row_ptr[n] = rp;
    cursor[n] = rp;
    if (n == NN - 1) row_ptr[NN] = rp + v;
  }
}

__global__ void k_scatter(const int* __restrict__ src, const int* __restrict__ dst,
                          int* __restrict__ cursor, int* __restrict__ csr_src) {
  int i = blockIdx.x * blockDim.x + threadIdx.x;
  if (i < NE) {
    int d = dst[i];
    int pos = atomicAdd(&cursor[d], 1);
    csr_src[pos] = src[i];
  }
}

// ---------------- weight pack (f32 -> bf16, concat) ----------------
__global__ void k_packw(const float* __restrict__ w1l, const float* __restrict__ w1r,
                        const float* __restrict__ w2l, const float* __restrict__ w2r,
                        unsigned short* __restrict__ Wc, unsigned short* __restrict__ W2c) {
  int i = blockIdx.x * blockDim.x + threadIdx.x;
  if (i < 256 * 256) {
    int o = i >> 8, k = i & 255;
    float v = (k < 128) ? w1l[o * 128 + k] : w1r[o * 128 + (k - 128)];
    Wc[i] = f2bf(v);
  }
  int j = i - 256 * 256;
  if (j >= 0 && j < 80 * 256) {
    int o = j >> 8, k = j & 255;
    float v = (o < 40) ? w2l[o * 256 + k] : w2r[(o - 40) * 256 + k];
    W2c[j] = f2bf(v);
  }
}

// ---------------- layer-1 aggregation: A1 = [mean-agg(x) | x] in bf16 ----------------
__global__ void k_agg1(const float* __restrict__ x, const int* __restrict__ row_ptr,
                       const int* __restrict__ csr_src, unsigned short* __restrict__ A1) {
  int w = threadIdx.x >> 6, lane = threadIdx.x & 63;
  int node = blockIdx.x * 4 + w;
  if (node >= NN) return;
  int rs = row_ptr[node], re = row_ptr[node + 1];
  float a0 = 0.f, a1 = 0.f;
  const float* xp = x + 2 * lane;
  for (int e = rs; e < re; ++e) {
    int s = csr_src[e];
    float2 v = *(const float2*)(xp + (size_t)s * DF);
    a0 += v.x; a1 += v.y;
  }
  int deg = re - rs;
  float inv = 1.f / (float)(deg > 0 ? deg : 1);
  unsigned pack = ((unsigned)f2bf(a1 * inv) << 16) | f2bf(a0 * inv);
  *(unsigned*)(A1 + (size_t)node * 256 + 2 * lane) = pack;
  float2 xv = *(const float2*)(xp + (size_t)node * DF);
  unsigned pack2 = ((unsigned)f2bf(xv.y) << 16) | f2bf(xv.x);
  *(unsigned*)(A1 + (size_t)node * 256 + 128 + 2 * lane) = pack2;
}

// ---------------- GEMM1: H = relu(A1 @ Wc^T + b1), bf16 in/out, f32 acc ----------------
// BM=128 BN=128 BK=64, 4 waves (2x2), each wave 64x64 (4x4 16x16x32 frags)
__global__ __launch_bounds__(256) void k_gemm1(const unsigned short* __restrict__ A1,
                                               const unsigned short* __restrict__ Wc,
                                               const float* __restrict__ b1,
                                               unsigned short* __restrict__ H) {
  __shared__ __align__(16) unsigned short sA[128 * 64];
  __shared__ __align__(16) unsigned short sB[128 * 64];
  int tid = threadIdx.x;
  int w = tid >> 6, lane = tid & 63;
  int brow = blockIdx.x * 128;
  int bcol = blockIdx.y * 128;
  int wr = (w >> 1) * 64, wc = (w & 1) * 64;
  f32x4 acc[4][4] = {};

  for (int kt = 0; kt < 4; ++kt) {
    // stage A and B tiles: 1024 16B chunks each; swizzled source, linear LDS dest
#pragma unroll
    for (int t = 0; t < 4; ++t) {
      int c = (t * 4 + w) * 64 + lane;
      int r = c >> 3, cc = c & 7;
      int scc = cc ^ (r & 7);
      int gr = brow + r; if (gr > NN - 1) gr = NN - 1;
      gload16(A1 + (size_t)gr * 256 + kt * 64 + scc * 8, sA + c * 8);
    }
#pragma unroll
    for (int t = 0; t < 4; ++t) {
      int c = (t * 4 + w) * 64 + lane;
      int r = c >> 3, cc = c & 7;
      int scc = cc ^ (r & 7);
      gload16(Wc + (size_t)(bcol + r) * 256 + kt * 64 + scc * 8, sB + c * 8);
    }
    __syncthreads();
#pragma unroll
    for (int kg = 0; kg < 2; ++kg) {
      short8 af[4], bfr[4];
#pragma unroll
      for (int m = 0; m < 4; ++m) {
        int row = wr + m * 16 + (lane & 15);
        int cch = (kg * 4 + (lane >> 4)) ^ (row & 7);
        af[m] = *(const short8*)(sA + row * 64 + cch * 8);
      }
#pragma unroll
      for (int n = 0; n < 4; ++n) {
        int row = wc + n * 16 + (lane & 15);
        int cch = (kg * 4 + (lane >> 4)) ^ (row & 7);
        bfr[n] = *(const short8*)(sB + row * 64 + cch * 8);
      }
#pragma unroll
      for (int m = 0; m < 4; ++m)
#pragma unroll
        for (int n = 0; n < 4; ++n)
          acc[m][n] = __builtin_amdgcn_mfma_f32_16x16x32_bf16(af[m], bfr[n], acc[m][n], 0, 0, 0);
    }
    __syncthreads();
  }

  int colbase = bcol + wc + (lane & 15);
  int rowbase = brow + wr + (lane >> 4) * 4;
#pragma unroll
  for (int n = 0; n < 4; ++n) {
    int col = colbase + n * 16;
    float bias = b1[col];
#pragma unroll
    for (int m = 0; m < 4; ++m) {
      int row0 = rowbase + m * 16;
#pragma unroll
      for (int q = 0; q < 4; ++q) {
        int row = row0 + q;
        if (row < NN) {
          float v = acc[m][n][q] + bias;
          v = v > 0.f ? v : 0.f;
          H[(size_t)row * 256 + col] = f2bf(v);
        }
      }
    }
  }
}

// ---------------- GEMM2: P = H @ W2c^T (cols 0..39 = p, 40..79 = r), f32 out ----------------
// BM=128 BN=80 BK=64, 4 waves stacked in M, each wave 32x80 (2x5 frags)
__global__ __launch_bounds__(256) void k_gemm2(const unsigned short* __restrict__ H,
                                               const unsigned short* __restrict__ W2c,
                                               float* __restrict__ P) {
  __shared__ __align__(16) unsigned short sA[128 * 64];
  __shared__ __align__(16) unsigned short sB[80 * 64];
  int tid = threadIdx.x;
  int w = tid >> 6, lane = tid & 63;
  int brow = blockIdx.x * 128;
  f32x4 acc[2][5] = {};

  for (int kt = 0; kt < 4; ++kt) {
#pragma unroll
    for (int t = 0; t < 4; ++t) {
      int c = (t * 4 + w) * 64 + lane;
      int r = c >> 3, cc = c & 7;
      int scc = cc ^ (r & 7);
      int gr = brow + r; if (gr > NN - 1) gr = NN - 1;
      gload16(H + (size_t)gr * 256 + kt * 64 + scc * 8, sA + c * 8);
    }
    for (int g = w; g < 10; g += 4) {
      int c = g * 64 + lane;
      int r = c >> 3, cc = c & 7;
      int scc = cc ^ (r & 7);
      gload16(W2c + (size_t)r * 256 + kt * 64 + scc * 8, sB + c * 8);
    }
    __syncthreads();
#pragma unroll
    for (int kg = 0; kg < 2; ++kg) {
      short8 af[2], bfr[5];
#pragma unroll
      for (int m = 0; m < 2; ++m) {
        int row = w * 32 + m * 16 + (lane & 15);
        int cch = (kg * 4 + (lane >> 4)) ^ (row & 7);
        af[m] = *(const short8*)(sA + row * 64 + cch * 8);
      }
#pragma unroll
      for (int n = 0; n < 5; ++n) {
        int row = n * 16 + (lane & 15);
        int cch = (kg * 4 + (lane >> 4)) ^ (row & 7);
        bfr[n] = *(const short8*)(sB + row * 64 + cch * 8);
      }
#pragma unroll
      for (int m = 0; m < 2; ++m)
#pragma unroll
        for (int n = 0; n < 5; ++n)
          acc[m][n] = __builtin_amdgcn_mfma_f32_16x16x32_bf16(af[m], bfr[n], acc[m][n], 0, 0, 0);
    }
    __syncthreads();
  }

  int colbase = lane & 15;
  int rowbase = brow + w * 32 + (lane >> 4) * 4;
#pragma unroll
  for (int m = 0; m < 2; ++m) {
#pragma unroll
    for (int n = 0; n < 5; ++n) {
      int col = colbase + n * 16;
#pragma unroll
      for (int q = 0; q < 4; ++q) {
        int row = rowbase + m * 16 + q;
        if (row < NN) P[(size_t)row * 80 + col] = acc[m][n][q];
      }
    }
  }
}

// ---------------- final: out = log_softmax(mean-agg(p) + b2 + r) ----------------
__global__ void k_final(const float* __restrict__ P, const int* __restrict__ row_ptr,
                        const int* __restrict__ csr_src, const float* __restrict__ b2,
                        float* __restrict__ out) {
  int w = threadIdx.x >> 6, lane = threadIdx.x & 63;
  int node = blockIdx.x * 4 + w;
  if (node >= NN) return;
  int rs = row_ptr[node], re = row_ptr[node + 1];
  bool act = lane < NC;
  float sum = 0.f;
  for (int e = rs; e < re; ++e) {
    int s = csr_src[e];
    if (act) sum += P[(size_t)s * 80 + lane];
  }
  float r = act ? P[(size_t)node * 80 + 40 + lane] : 0.f;
  float bv = act ? b2[lane] : 0.f;
  int deg = re - rs;
  float v = sum / (float)(deg > 0 ? deg : 1) + r + bv;
  float mx = act ? v : -1e30f;
  for (int o = 32; o > 0; o >>= 1) mx = fmaxf(mx, __shfl_xor(mx, o));
  float ex = act ? __expf(v - mx) : 0.f;
  float sm = ex;
  for (int o = 32; o > 0; o >>= 1) sm += __shfl_xor(sm, o);
  float ls = v - mx - __logf(sm);
  if (act) out[(size_t)node * NC + lane] = ls;
}

extern "C" void kernel_launch(void* const* d_in, const int* in_sizes, int n_in,
                              void* d_out, int out_size, void* d_ws, size_t ws_size,
                              hipStream_t stream) {
  const float* x   = (const float*)d_in[0];
  const int*   ei  = (const int*)d_in[1];
  const float* w1l = (const float*)d_in[2];
  const float* b1  = (const float*)d_in[3];
  const float* w1r = (const float*)d_in[4];
  const float* w2l = (const float*)d_in[5];
  const float* b2  = (const float*)d_in[6];
  const float* w2r = (const float*)d_in[7];
  float* out = (float*)d_out;
  const int* src = ei;
  const int* dst = ei + NE;

  char* ws = (char*)d_ws;
  size_t off = 0;
  auto alloc = [&](size_t bytes) -> char* {
    char* p = ws + off;
    off = (off + bytes + 255) & ~(size_t)255;
    return p;
  };
  int* cnt       = (int*)alloc((size_t)NN * 4);
  int* row_ptr   = (int*)alloc((size_t)(NN + 1) * 4);
  int* cursor    = (int*)alloc((size_t)NN * 4);
  int* chunk_off = (int*)alloc(800 * 4);
  int* csr       = (int*)alloc((size_t)NE * 4);
  unsigned short* Wc  = (unsigned short*)alloc(256 * 256 * 2);
  unsigned short* W2c = (unsigned short*)alloc(80 * 256 * 2);
  unsigned short* A1  = (unsigned short*)alloc((size_t)NN * 256 * 2);
  unsigned short* H   = (unsigned short*)alloc((size_t)NN * 256 * 2);
  float* P            = (float*)alloc((size_t)NN * 80 * 4);

  hipMemsetAsync(cnt, 0, (size_t)NN * 4, stream);
  k_hist<<<(NE + 255) / 256, 256, 0, stream>>>(dst, cnt);
  k_scanA<<<1, 1024, 0, stream>>>(cnt, chunk_off);
  k_scanB<<<NCHUNK, 128, 0, stream>>>(cnt, chunk_off, row_ptr, cursor);
  k_scatter<<<(NE + 255) / 256, 256, 0, stream>>>(src, dst, cursor, csr);
  k_packw<<<336, 256, 0, stream>>>(w1l, w1r, w2l, w2r, Wc, W2c);
  k_agg1<<<(NN + 3) / 4, 256, 0, stream>>>(x, row_ptr, csr, A1);
  dim3 g1((NN + 127) / 128, 2);
  k_gemm1<<<g1, 256, 0, stream>>>(A1, Wc, b1, H);
  k_gemm2<<<(NN + 127) / 128, 256, 0, stream>>>(H, W2c, P);
  k_final<<<(NN + 3) / 4, 256, 0, stream>>>(P, row_ptr, csr, b2, out);
}

// Round 2
// 616.647 us; speedup vs baseline: 1.1925x; 1.1925x over previous
//
#include <hip/hip_runtime.h>
#include <hip/hip_bf16.h>
#include <stdint.h>

#define NN 100000
#define NE 1600000
#define DF 128
#define DH 256
#define NC 40
#define NCHUNK 782   // ceil(NN/128)

typedef __attribute__((ext_vector_type(8))) short short8;
typedef __attribute__((ext_vector_type(4))) float f32x4;

typedef const __attribute__((address_space(1))) unsigned int* gas1;
typedef __attribute__((address_space(3))) unsigned int* las3;

__device__ __forceinline__ void gload16(const void* g, void* l) {
  __builtin_amdgcn_global_load_lds((gas1)g, (las3)l, 16, 0, 0);
}

__device__ __forceinline__ unsigned short f2bf(float f) {
  union { float f; unsigned u; } v; v.f = f;
  unsigned r = v.u + 0x7FFFu + ((v.u >> 16) & 1u);
  return (unsigned short)(r >> 16);
}
__device__ __forceinline__ float bflo(unsigned u) {
  union { unsigned u; float f; } v; v.u = u << 16; return v.f;
}
__device__ __forceinline__ float bfhi(unsigned u) {
  union { unsigned u; float f; } v; v.u = u & 0xFFFF0000u; return v.f;
}
__device__ __forceinline__ float bf2f(unsigned short s) {
  union { unsigned u; float f; } v; v.u = (unsigned)s << 16; return v.f;
}

// ---------------- x -> bf16 pre-convert ----------------
__global__ void k_xbf16(const float* __restrict__ x, unsigned* __restrict__ xb) {
  int i = blockIdx.x * blockDim.x + threadIdx.x;  // one u32 (2 bf16) per thread
  if (i < NN * 64) {
    float2 v = ((const float2*)x)[i];
    xb[i] = ((unsigned)f2bf(v.y) << 16) | f2bf(v.x);
  }
}

// ---------------- CSR build ----------------
__global__ void k_hist(const int* __restrict__ dst, int* __restrict__ cnt) {
  int i = blockIdx.x * blockDim.x + threadIdx.x;
  if (i < NE) atomicAdd(&cnt[dst[i]], 1);
}

__global__ void k_scanA(const int* __restrict__ cnt, int* __restrict__ chunk_off) {
  __shared__ int part[800];
  int tid = threadIdx.x;
  if (tid < NCHUNK) {
    int s = 0, base = tid * 128;
    for (int j = 0; j < 128; ++j) { int idx = base + j; if (idx < NN) s += cnt[idx]; }
    part[tid] = s;
  }
  __syncthreads();
  if (tid == 0) {
    int run = 0;
    for (int i = 0; i < NCHUNK; ++i) { int t = part[i]; part[i] = run; run += t; }
  }
  __syncthreads();
  if (tid < NCHUNK) chunk_off[tid] = part[tid];
}

__global__ void k_scanB(const int* __restrict__ cnt, const int* __restrict__ chunk_off,
                        int* __restrict__ row_ptr, int* __restrict__ cursor) {
  __shared__ int s[128];
  int tid = threadIdx.x;
  int n = blockIdx.x * 128 + tid;
  int v = (n < NN) ? cnt[n] : 0;
  s[tid] = v;
  __syncthreads();
  for (int off = 1; off < 128; off <<= 1) {
    int add = (tid >= off) ? s[tid - off] : 0;
    __syncthreads();
    s[tid] += add;
    __syncthreads();
  }
  int incl = s[tid];
  int excl = incl - v;
  int rp = chunk_off[blockIdx.x] + excl;
  if (n < NN) {
    row_ptr[n] = rp;
    cursor[n] = rp;
    if (n == NN - 1) row_ptr[NN] = rp + v;
  }
}

__global__ void k_scatter(const int* __restrict__ src, const int* __restrict__ dst,
                          int* __restrict__ cursor, int* __restrict__ csr_src) {
  int i = blockIdx.x * blockDim.x + threadIdx.x;
  if (i < NE) {
    int d = dst[i];
    int pos = atomicAdd(&cursor[d], 1);
    csr_src[pos] = src[i];
  }
}

// ---------------- weight pack (f32 -> bf16, concat) ----------------
__global__ void k_packw(const float* __restrict__ w1l, const float* __restrict__ w1r,
                        const float* __restrict__ w2l, const float* __restrict__ w2r,
                        unsigned short* __restrict__ Wc, unsigned short* __restrict__ W2c) {
  int i = blockIdx.x * blockDim.x + threadIdx.x;
  if (i < 256 * 256) {
    int o = i >> 8, k = i & 255;
    float v = (k < 128) ? w1l[o * 128 + k] : w1r[o * 128 + (k - 128)];
    Wc[i] = f2bf(v);
  }
  int j = i - 256 * 256;
  if (j >= 0 && j < 80 * 256) {
    int o = j >> 8, k = j & 255;
    float v = (o < 40) ? w2l[o * 256 + k] : w2r[(o - 40) * 256 + k];
    W2c[j] = f2bf(v);
  }
}

// ---------------- layer-1 aggregation: A1 = [mean-agg(xb) | xb] in bf16 ----------------
__global__ void k_agg1(const unsigned* __restrict__ xb, const int* __restrict__ row_ptr,
                       const int* __restrict__ csr_src, unsigned* __restrict__ A1) {
  int w = threadIdx.x >> 6, lane = threadIdx.x & 63;
  int node = blockIdx.x * 4 + w;
  if (node >= NN) return;
  int rs = row_ptr[node], re = row_ptr[node + 1];
  float a0 = 0.f, a1 = 0.f;
  int e = rs;
  for (; e + 1 < re; e += 2) {
    int s0 = csr_src[e], s1 = csr_src[e + 1];
    unsigned v0 = xb[(size_t)s0 * 64 + lane];
    unsigned v1 = xb[(size_t)s1 * 64 + lane];
    a0 += bflo(v0) + bflo(v1);
    a1 += bfhi(v0) + bfhi(v1);
  }
  if (e < re) {
    unsigned v0 = xb[(size_t)csr_src[e] * 64 + lane];
    a0 += bflo(v0); a1 += bfhi(v0);
  }
  int deg = re - rs;
  float inv = 1.f / (float)(deg > 0 ? deg : 1);
  unsigned pack = ((unsigned)f2bf(a1 * inv) << 16) | f2bf(a0 * inv);
  A1[(size_t)node * 128 + lane] = pack;
  A1[(size_t)node * 128 + 64 + lane] = xb[(size_t)node * 64 + lane];
}

// ---------------- GEMM1: H = relu(A1 @ Wc^T + b1), bf16 in/out, f32 acc ----------------
__global__ __launch_bounds__(256) void k_gemm1(const unsigned short* __restrict__ A1,
                                               const unsigned short* __restrict__ Wc,
                                               const float* __restrict__ b1,
                                               unsigned short* __restrict__ H) {
  __shared__ __align__(16) unsigned short sA[128 * 64];
  __shared__ __align__(16) unsigned short sB[128 * 64];
  int tid = threadIdx.x;
  int w = tid >> 6, lane = tid & 63;
  int brow = blockIdx.x * 128;
  int bcol = blockIdx.y * 128;
  int wr = (w >> 1) * 64, wc = (w & 1) * 64;
  f32x4 acc[4][4] = {};

  for (int kt = 0; kt < 4; ++kt) {
#pragma unroll
    for (int t = 0; t < 4; ++t) {
      int c = (t * 4 + w) * 64 + lane;
      int r = c >> 3, cc = c & 7;
      int scc = cc ^ (r & 7);
      int gr = brow + r; if (gr > NN - 1) gr = NN - 1;
      gload16(A1 + (size_t)gr * 256 + kt * 64 + scc * 8, sA + c * 8);
    }
#pragma unroll
    for (int t = 0; t < 4; ++t) {
      int c = (t * 4 + w) * 64 + lane;
      int r = c >> 3, cc = c & 7;
      int scc = cc ^ (r & 7);
      gload16(Wc + (size_t)(bcol + r) * 256 + kt * 64 + scc * 8, sB + c * 8);
    }
    __syncthreads();
#pragma unroll
    for (int kg = 0; kg < 2; ++kg) {
      short8 af[4], bfr[4];
#pragma unroll
      for (int m = 0; m < 4; ++m) {
        int row = wr + m * 16 + (lane & 15);
        int cch = (kg * 4 + (lane >> 4)) ^ (row & 7);
        af[m] = *(const short8*)(sA + row * 64 + cch * 8);
      }
#pragma unroll
      for (int n = 0; n < 4; ++n) {
        int row = wc + n * 16 + (lane & 15);
        int cch = (kg * 4 + (lane >> 4)) ^ (row & 7);
        bfr[n] = *(const short8*)(sB + row * 64 + cch * 8);
      }
#pragma unroll
      for (int m = 0; m < 4; ++m)
#pragma unroll
        for (int n = 0; n < 4; ++n)
          acc[m][n] = __builtin_amdgcn_mfma_f32_16x16x32_bf16(af[m], bfr[n], acc[m][n], 0, 0, 0);
    }
    __syncthreads();
  }

  int colbase = bcol + wc + (lane & 15);
  int rowbase = brow + wr + (lane >> 4) * 4;
#pragma unroll
  for (int n = 0; n < 4; ++n) {
    int col = colbase + n * 16;
    float bias = b1[col];
#pragma unroll
    for (int m = 0; m < 4; ++m) {
      int row0 = rowbase + m * 16;
#pragma unroll
      for (int q = 0; q < 4; ++q) {
        int row = row0 + q;
        if (row < NN) {
          float v = acc[m][n][q] + bias;
          v = v > 0.f ? v : 0.f;
          H[(size_t)row * 256 + col] = f2bf(v);
        }
      }
    }
  }
}

// ---------------- GEMM2: [p|r] = H @ W2c^T ; p -> bf16, r -> f32 ----------------
__global__ __launch_bounds__(256) void k_gemm2(const unsigned short* __restrict__ H,
                                               const unsigned short* __restrict__ W2c,
                                               unsigned short* __restrict__ Pb,
                                               float* __restrict__ R) {
  __shared__ __align__(16) unsigned short sA[128 * 64];
  __shared__ __align__(16) unsigned short sB[80 * 64];
  int tid = threadIdx.x;
  int w = tid >> 6, lane = tid & 63;
  int brow = blockIdx.x * 128;
  f32x4 acc[2][5] = {};

  for (int kt = 0; kt < 4; ++kt) {
#pragma unroll
    for (int t = 0; t < 4; ++t) {
      int c = (t * 4 + w) * 64 + lane;
      int r = c >> 3, cc = c & 7;
      int scc = cc ^ (r & 7);
      int gr = brow + r; if (gr > NN - 1) gr = NN - 1;
      gload16(H + (size_t)gr * 256 + kt * 64 + scc * 8, sA + c * 8);
    }
    for (int g = w; g < 10; g += 4) {
      int c = g * 64 + lane;
      int r = c >> 3, cc = c & 7;
      int scc = cc ^ (r & 7);
      gload16(W2c + (size_t)r * 256 + kt * 64 + scc * 8, sB + c * 8);
    }
    __syncthreads();
#pragma unroll
    for (int kg = 0; kg < 2; ++kg) {
      short8 af[2], bfr[5];
#pragma unroll
      for (int m = 0; m < 2; ++m) {
        int row = w * 32 + m * 16 + (lane & 15);
        int cch = (kg * 4 + (lane >> 4)) ^ (row & 7);
        af[m] = *(const short8*)(sA + row * 64 + cch * 8);
      }
#pragma unroll
      for (int n = 0; n < 5; ++n) {
        int row = n * 16 + (lane & 15);
        int cch = (kg * 4 + (lane >> 4)) ^ (row & 7);
        bfr[n] = *(const short8*)(sB + row * 64 + cch * 8);
      }
#pragma unroll
      for (int m = 0; m < 2; ++m)
#pragma unroll
        for (int n = 0; n < 5; ++n)
          acc[m][n] = __builtin_amdgcn_mfma_f32_16x16x32_bf16(af[m], bfr[n], acc[m][n], 0, 0, 0);
    }
    __syncthreads();
  }

  int colbase = lane & 15;
  int rowbase = brow + w * 32 + (lane >> 4) * 4;
#pragma unroll
  for (int m = 0; m < 2; ++m) {
#pragma unroll
    for (int n = 0; n < 5; ++n) {
      int col = colbase + n * 16;
#pragma unroll
      for (int q = 0; q < 4; ++q) {
        int row = rowbase + m * 16 + q;
        if (row < NN) {
          float v = acc[m][n][q];
          if (col < NC) Pb[(size_t)row * NC + col] = f2bf(v);
          else          R[(size_t)row * NC + (col - NC)] = v;
        }
      }
    }
  }
}

// ---------------- final: out = log_softmax(mean-agg(p) + b2 + r) ----------------
__global__ void k_final(const unsigned short* __restrict__ Pb, const float* __restrict__ R,
                        const int* __restrict__ row_ptr, const int* __restrict__ csr_src,
                        const float* __restrict__ b2, float* __restrict__ out) {
  int w = threadIdx.x >> 6, lane = threadIdx.x & 63;
  int node = blockIdx.x * 4 + w;
  if (node >= NN) return;
  int rs = row_ptr[node], re = row_ptr[node + 1];
  bool act = lane < NC;
  float sum = 0.f;
  int e = rs;
  for (; e + 1 < re; e += 2) {
    int s0 = csr_src[e], s1 = csr_src[e + 1];
    if (act) {
      sum += bf2f(Pb[(size_t)s0 * NC + lane]);
      sum += bf2f(Pb[(size_t)s1 * NC + lane]);
    }
  }
  if (e < re) {
    int s0 = csr_src[e];
    if (act) sum += bf2f(Pb[(size_t)s0 * NC + lane]);
  }
  float r = act ? R[(size_t)node * NC + lane] : 0.f;
  float bv = act ? b2[lane] : 0.f;
  int deg = re - rs;
  float v = sum / (float)(deg > 0 ? deg : 1) + r + bv;
  float mx = act ? v : -1e30f;
  for (int o = 32; o > 0; o >>= 1) mx = fmaxf(mx, __shfl_xor(mx, o));
  float ex = act ? __expf(v - mx) : 0.f;
  float sm = ex;
  for (int o = 32; o > 0; o >>= 1) sm += __shfl_xor(sm, o);
  float ls = v - mx - __logf(sm);
  if (act) out[(size_t)node * NC + lane] = ls;
}

extern "C" void kernel_launch(void* const* d_in, const int* in_sizes, int n_in,
                              void* d_out, int out_size, void* d_ws, size_t ws_size,
                              hipStream_t stream) {
  const float* x   = (const float*)d_in[0];
  const int*   ei  = (const int*)d_in[1];
  const float* w1l = (const float*)d_in[2];
  const float* b1  = (const float*)d_in[3];
  const float* w1r = (const float*)d_in[4];
  const float* w2l = (const float*)d_in[5];
  const float* b2  = (const float*)d_in[6];
  const float* w2r = (const float*)d_in[7];
  float* out = (float*)d_out;
  const int* src = ei;
  const int* dst = ei + NE;

  char* ws = (char*)d_ws;
  size_t off = 0;
  auto alloc = [&](size_t bytes) -> char* {
    char* p = ws + off;
    off = (off + bytes + 255) & ~(size_t)255;
    return p;
  };
  int* cnt       = (int*)alloc((size_t)NN * 4);
  int* row_ptr   = (int*)alloc((size_t)(NN + 1) * 4);
  int* cursor    = (int*)alloc((size_t)NN * 4);
  int* chunk_off = (int*)alloc(800 * 4);
  int* csr       = (int*)alloc((size_t)NE * 4);
  unsigned short* Wc  = (unsigned short*)alloc(256 * 256 * 2);
  unsigned short* W2c = (unsigned short*)alloc(80 * 256 * 2);
  unsigned*       xb  = (unsigned*)alloc((size_t)NN * 64 * 4);
  unsigned*       A1  = (unsigned*)alloc((size_t)NN * 128 * 4);
  unsigned short* H   = (unsigned short*)alloc((size_t)NN * 256 * 2);
  unsigned short* Pb  = (unsigned short*)alloc((size_t)NN * NC * 2);
  float*          R   = (float*)alloc((size_t)NN * NC * 4);

  hipMemsetAsync(cnt, 0, (size_t)NN * 4, stream);
  k_hist<<<(NE + 255) / 256, 256, 0, stream>>>(dst, cnt);
  k_xbf16<<<(NN * 64 + 255) / 256, 256, 0, stream>>>(x, xb);
  k_scanA<<<1, 1024, 0, stream>>>(cnt, chunk_off);
  k_scanB<<<NCHUNK, 128, 0, stream>>>(cnt, chunk_off, row_ptr, cursor);
  k_scatter<<<(NE + 255) / 256, 256, 0, stream>>>(src, dst, cursor, csr);
  k_packw<<<336, 256, 0, stream>>>(w1l, w1r, w2l, w2r, Wc, W2c);
  k_agg1<<<(NN + 3) / 4, 256, 0, stream>>>(xb, row_ptr, csr, A1);
  dim3 g1((NN + 127) / 128, 2);
  k_gemm1<<<g1, 256, 0, stream>>>((const unsigned short*)A1, Wc, b1, H);
  k_gemm2<<<(NN + 127) / 128, 256, 0, stream>>>(H, W2c, Pb, R);
  k_final<<<(NN + 3) / 4, 256, 0, stream>>>(Pb, R, row_ptr, csr, b2, out);
}

// Round 4
// 418.224 us; speedup vs baseline: 1.7583x; 1.4744x over previous
//
#include <hip/hip_runtime.h>
#include <hip/hip_bf16.h>
#include <stdint.h>

#define NN 100000
#define NE 1600000
#define DF 128
#define DH 256
#define NC 40
#define BSHIFT 8
#define NBKT 391          // ceil(NN/256) buckets, bucket = dst>>8
#define EPB 8192          // edges per k_bin block
#define NBIN_BLOCKS ((NE + EPB - 1) / EPB)   // 196

typedef __attribute__((ext_vector_type(8))) short short8;
typedef __attribute__((ext_vector_type(4))) float f32x4;

typedef const __attribute__((address_space(1))) unsigned int* gas1;
typedef __attribute__((address_space(3))) unsigned int* las3;

__device__ __forceinline__ void gload16(const void* g, void* l) {
  __builtin_amdgcn_global_load_lds((gas1)g, (las3)l, 16, 0, 0);
}

__device__ __forceinline__ unsigned short f2bf(float f) {
  union { float f; unsigned u; } v; v.f = f;
  unsigned r = v.u + 0x7FFFu + ((v.u >> 16) & 1u);
  return (unsigned short)(r >> 16);
}
__device__ __forceinline__ float bflo(unsigned u) {
  union { unsigned u; float f; } v; v.u = u << 16; return v.f;
}
__device__ __forceinline__ float bfhi(unsigned u) {
  union { unsigned u; float f; } v; v.u = u & 0xFFFF0000u; return v.f;
}
__device__ __forceinline__ float bf2f(unsigned short s) {
  union { unsigned u; float f; } v; v.u = (unsigned)s << 16; return v.f;
}

// ---------------- x -> bf16 pre-convert ----------------
__global__ void k_xbf16(const float* __restrict__ x, unsigned* __restrict__ xb) {
  int i = blockIdx.x * blockDim.x + threadIdx.x;
  if (i < NN * 64) {
    float2 v = ((const float2*)x)[i];
    xb[i] = ((unsigned)f2bf(v.y) << 16) | f2bf(v.x);
  }
}

// ---------------- CSR build: bucket counting sort ----------------
// pass 0: bucket histogram (LDS-aggregated)
__global__ __launch_bounds__(256) void k_bhist(const int* __restrict__ dst, int* __restrict__ bcnt) {
  __shared__ int h[NBKT];
  int tid = threadIdx.x;
  for (int b = tid; b < NBKT; b += 256) h[b] = 0;
  __syncthreads();
  int base = blockIdx.x * EPB;
  int n = NE - base; if (n > EPB) n = EPB;
  for (int i = tid; i < n; i += 256) atomicAdd(&h[dst[base + i] >> BSHIFT], 1);
  __syncthreads();
  for (int b = tid; b < NBKT; b += 256) if (h[b]) atomicAdd(&bcnt[b], h[b]);
}

// pass 0.5: scan buckets -> bases (also CSR bucket bases); init cursors
__global__ __launch_bounds__(512) void k_bscan(const int* __restrict__ bcnt,
                                               int* __restrict__ boff, int* __restrict__ bcur) {
  __shared__ int s[512];
  int tid = threadIdx.x;
  int v = (tid < NBKT) ? bcnt[tid] : 0;
  s[tid] = v;
  __syncthreads();
  for (int off = 1; off < 512; off <<= 1) {
    int a = (tid >= off) ? s[tid - off] : 0;
    __syncthreads();
    s[tid] += a;
    __syncthreads();
  }
  int excl = s[tid] - v;
  if (tid < NBKT) { boff[tid] = excl; bcur[tid] = excl; }
  if (tid == 0) boff[NBKT] = s[511];
}

// pass 1: bin edges into bucket-grouped staging, packed src|(dlocal<<17)
__global__ __launch_bounds__(256) void k_bin(const int* __restrict__ src, const int* __restrict__ dst,
                                             int* __restrict__ bcur, unsigned* __restrict__ pairs) {
  __shared__ int hcnt[NBKT];
  __shared__ int hbase[NBKT];
  int tid = threadIdx.x;
  for (int b = tid; b < NBKT; b += 256) hcnt[b] = 0;
  __syncthreads();
  int base = blockIdx.x * EPB;
  int n = NE - base; if (n > EPB) n = EPB;
  for (int i = tid; i < n; i += 256) atomicAdd(&hcnt[dst[base + i] >> BSHIFT], 1);
  __syncthreads();
  for (int b = tid; b < NBKT; b += 256) hbase[b] = hcnt[b] ? atomicAdd(&bcur[b], hcnt[b]) : 0;
  __syncthreads();
  for (int b = tid; b < NBKT; b += 256) hcnt[b] = 0;
  __syncthreads();
  for (int i = tid; i < n; i += 256) {
    int s = src[base + i], d = dst[base + i];
    int b = d >> BSHIFT;
    int slot = atomicAdd(&hcnt[b], 1);
    pairs[hbase[b] + slot] = (unsigned)s | ((unsigned)(d & 255) << 17);
  }
}

// pass 2: per-bucket local CSR: row_ptr + csr_src
__global__ __launch_bounds__(256) void k_csr(const unsigned* __restrict__ pairs,
                                             const int* __restrict__ boff,
                                             int* __restrict__ row_ptr, int* __restrict__ csr) {
  __shared__ int ncnt[256];
  __shared__ int noff[256];
  int tid = threadIdx.x;
  int b = blockIdx.x;
  int base = boff[b], end = boff[b + 1];
  ncnt[tid] = 0;
  __syncthreads();
  for (int e = base + tid; e < end; e += 256) atomicAdd(&ncnt[pairs[e] >> 17], 1);
  __syncthreads();
  int v = ncnt[tid];
  noff[tid] = v;
  __syncthreads();
  for (int off = 1; off < 256; off <<= 1) {
    int a = (tid >= off) ? noff[tid - off] : 0;
    __syncthreads();
    noff[tid] += a;
    __syncthreads();
  }
  int excl = noff[tid] - v;
  __syncthreads();
  noff[tid] = excl;
  ncnt[tid] = 0;
  __syncthreads();
  int gnode = (b << BSHIFT) + tid;
  if (gnode < NN) row_ptr[gnode] = base + excl;
  if (b == NBKT - 1 && tid == 0) row_ptr[NN] = NE;
  for (int e = base + tid; e < end; e += 256) {
    unsigned p = pairs[e];
    int ld = p >> 17;
    int slot = atomicAdd(&ncnt[ld], 1);
    csr[base + noff[ld] + slot] = (int)(p & 0x1FFFFu);
  }
}

// ---------------- weight pack (f32 -> bf16, concat) ----------------
__global__ void k_packw(const float* __restrict__ w1l, const float* __restrict__ w1r,
                        const float* __restrict__ w2l, const float* __restrict__ w2r,
                        unsigned short* __restrict__ Wc, unsigned short* __restrict__ W2c) {
  int i = blockIdx.x * blockDim.x + threadIdx.x;
  if (i < 256 * 256) {
    int o = i >> 8, k = i & 255;
    float v = (k < 128) ? w1l[o * 128 + k] : w1r[o * 128 + (k - 128)];
    Wc[i] = f2bf(v);
  }
  int j = i - 256 * 256;
  if (j >= 0 && j < 80 * 256) {
    int o = j >> 8, k = j & 255;
    float v = (o < 40) ? w2l[o * 256 + k] : w2r[(o - 40) * 256 + k];
    W2c[j] = f2bf(v);
  }
}

// ---------------- layer-1 aggregation: A1 = [mean-agg(xb) | xb] in bf16 ----------------
__global__ void k_agg1(const unsigned* __restrict__ xb, const int* __restrict__ row_ptr,
                       const int* __restrict__ csr_src, unsigned* __restrict__ A1) {
  int w = threadIdx.x >> 6, lane = threadIdx.x & 63;
  int node = blockIdx.x * 4 + w;
  if (node >= NN) return;
  int rs = row_ptr[node], re = row_ptr[node + 1];
  float a0 = 0.f, a1 = 0.f;
  int e = rs;
  for (; e + 3 < re; e += 4) {
    int s0 = csr_src[e], s1 = csr_src[e + 1], s2 = csr_src[e + 2], s3 = csr_src[e + 3];
    unsigned v0 = xb[(size_t)s0 * 64 + lane];
    unsigned v1 = xb[(size_t)s1 * 64 + lane];
    unsigned v2 = xb[(size_t)s2 * 64 + lane];
    unsigned v3 = xb[(size_t)s3 * 64 + lane];
    a0 += bflo(v0) + bflo(v1) + bflo(v2) + bflo(v3);
    a1 += bfhi(v0) + bfhi(v1) + bfhi(v2) + bfhi(v3);
  }
  for (; e < re; ++e) {
    unsigned v0 = xb[(size_t)csr_src[e] * 64 + lane];
    a0 += bflo(v0); a1 += bfhi(v0);
  }
  int deg = re - rs;
  float inv = 1.f / (float)(deg > 0 ? deg : 1);
  unsigned pack = ((unsigned)f2bf(a1 * inv) << 16) | f2bf(a0 * inv);
  A1[(size_t)node * 128 + lane] = pack;
  A1[(size_t)node * 128 + 64 + lane] = xb[(size_t)node * 64 + lane];
}

// ---------------- GEMM1: H = relu(A1 @ Wc^T + b1), bf16 in/out, f32 acc ----------------
__global__ __launch_bounds__(256) void k_gemm1(const unsigned short* __restrict__ A1,
                                               const unsigned short* __restrict__ Wc,
                                               const float* __restrict__ b1,
                                               unsigned short* __restrict__ H) {
  __shared__ __align__(16) unsigned short sA[128 * 64];
  __shared__ __align__(16) unsigned short sB[128 * 64];
  int tid = threadIdx.x;
  int w = tid >> 6, lane = tid & 63;
  int brow = blockIdx.x * 128;
  int bcol = blockIdx.y * 128;
  int wr = (w >> 1) * 64, wc = (w & 1) * 64;
  f32x4 acc[4][4] = {};

  for (int kt = 0; kt < 4; ++kt) {
#pragma unroll
    for (int t = 0; t < 4; ++t) {
      int c = (t * 4 + w) * 64 + lane;
      int r = c >> 3, cc = c & 7;
      int scc = cc ^ (r & 7);
      int gr = brow + r; if (gr > NN - 1) gr = NN - 1;
      gload16(A1 + (size_t)gr * 256 + kt * 64 + scc * 8, sA + c * 8);
    }
#pragma unroll
    for (int t = 0; t < 4; ++t) {
      int c = (t * 4 + w) * 64 + lane;
      int r = c >> 3, cc = c & 7;
      int scc = cc ^ (r & 7);
      gload16(Wc + (size_t)(bcol + r) * 256 + kt * 64 + scc * 8, sB + c * 8);
    }
    __syncthreads();
#pragma unroll
    for (int kg = 0; kg < 2; ++kg) {
      short8 af[4], bfr[4];
#pragma unroll
      for (int m = 0; m < 4; ++m) {
        int row = wr + m * 16 + (lane & 15);
        int cch = (kg * 4 + (lane >> 4)) ^ (row & 7);
        af[m] = *(const short8*)(sA + row * 64 + cch * 8);
      }
#pragma unroll
      for (int n = 0; n < 4; ++n) {
        int row = wc + n * 16 + (lane & 15);
        int cch = (kg * 4 + (lane >> 4)) ^ (row & 7);
        bfr[n] = *(const short8*)(sB + row * 64 + cch * 8);
      }
#pragma unroll
      for (int m = 0; m < 4; ++m)
#pragma unroll
        for (int n = 0; n < 4; ++n)
          acc[m][n] = __builtin_amdgcn_mfma_f32_16x16x32_bf16(af[m], bfr[n], acc[m][n], 0, 0, 0);
    }
    __syncthreads();
  }

  int colbase = bcol + wc + (lane & 15);
  int rowbase = brow + wr + (lane >> 4) * 4;
#pragma unroll
  for (int n = 0; n < 4; ++n) {
    int col = colbase + n * 16;
    float bias = b1[col];
#pragma unroll
    for (int m = 0; m < 4; ++m) {
      int row0 = rowbase + m * 16;
#pragma unroll
      for (int q = 0; q < 4; ++q) {
        int row = row0 + q;
        if (row < NN) {
          float v = acc[m][n][q] + bias;
          v = v > 0.f ? v : 0.f;
          H[(size_t)row * 256 + col] = f2bf(v);
        }
      }
    }
  }
}

// ---------------- GEMM2: [p|r] = H @ W2c^T ; p -> bf16, r -> f32 ----------------
__global__ __launch_bounds__(256) void k_gemm2(const unsigned short* __restrict__ H,
                                               const unsigned short* __restrict__ W2c,
                                               unsigned short* __restrict__ Pb,
                                               float* __restrict__ R) {
  __shared__ __align__(16) unsigned short sA[128 * 64];
  __shared__ __align__(16) unsigned short sB[80 * 64];
  int tid = threadIdx.x;
  int w = tid >> 6, lane = tid & 63;
  int brow = blockIdx.x * 128;
  f32x4 acc[2][5] = {};

  for (int kt = 0; kt < 4; ++kt) {
#pragma unroll
    for (int t = 0; t < 4; ++t) {
      int c = (t * 4 + w) * 64 + lane;
      int r = c >> 3, cc = c & 7;
      int scc = cc ^ (r & 7);
      int gr = brow + r; if (gr > NN - 1) gr = NN - 1;
      gload16(H + (size_t)gr * 256 + kt * 64 + scc * 8, sA + c * 8);
    }
    for (int g = w; g < 10; g += 4) {
      int c = g * 64 + lane;
      int r = c >> 3, cc = c & 7;
      int scc = cc ^ (r & 7);
      gload16(W2c + (size_t)r * 256 + kt * 64 + scc * 8, sB + c * 8);
    }
    __syncthreads();
#pragma unroll
    for (int kg = 0; kg < 2; ++kg) {
      short8 af[2], bfr[5];
#pragma unroll
      for (int m = 0; m < 2; ++m) {
        int row = w * 32 + m * 16 + (lane & 15);
        int cch = (kg * 4 + (lane >> 4)) ^ (row & 7);
        af[m] = *(const short8*)(sA + row * 64 + cch * 8);
      }
#pragma unroll
      for (int n = 0; n < 5; ++n) {
        int row = n * 16 + (lane & 15);
        int cch = (kg * 4 + (lane >> 4)) ^ (row & 7);
        bfr[n] = *(const short8*)(sB + row * 64 + cch * 8);
      }
#pragma unroll
      for (int m = 0; m < 2; ++m)
#pragma unroll
        for (int n = 0; n < 5; ++n)
          acc[m][n] = __builtin_amdgcn_mfma_f32_16x16x32_bf16(af[m], bfr[n], acc[m][n], 0, 0, 0);
    }
    __syncthreads();
  }

  int colbase = lane & 15;
  int rowbase = brow + w * 32 + (lane >> 4) * 4;
#pragma unroll
  for (int m = 0; m < 2; ++m) {
#pragma unroll
    for (int n = 0; n < 5; ++n) {
      int col = colbase + n * 16;
#pragma unroll
      for (int q = 0; q < 4; ++q) {
        int row = rowbase + m * 16 + q;
        if (row < NN) {
          float v = acc[m][n][q];
          if (col < NC) Pb[(size_t)row * NC + col] = f2bf(v);
          else          R[(size_t)row * NC + (col - NC)] = v;
        }
      }
    }
  }
}

// ---------------- final: out = log_softmax(mean-agg(p) + b2 + r) ----------------
__global__ void k_final(const unsigned short* __restrict__ Pb, const float* __restrict__ R,
                        const int* __restrict__ row_ptr, const int* __restrict__ csr_src,
                        const float* __restrict__ b2, float* __restrict__ out) {
  int w = threadIdx.x >> 6, lane = threadIdx.x & 63;
  int node = blockIdx.x * 4 + w;
  if (node >= NN) return;
  int rs = row_ptr[node], re = row_ptr[node + 1];
  bool act = lane < NC;
  float sum = 0.f;
  int e = rs;
  for (; e + 1 < re; e += 2) {
    int s0 = csr_src[e], s1 = csr_src[e + 1];
    if (act) {
      sum += bf2f(Pb[(size_t)s0 * NC + lane]);
      sum += bf2f(Pb[(size_t)s1 * NC + lane]);
    }
  }
  if (e < re) {
    int s0 = csr_src[e];
    if (act) sum += bf2f(Pb[(size_t)s0 * NC + lane]);
  }
  float r = act ? R[(size_t)node * NC + lane] : 0.f;
  float bv = act ? b2[lane] : 0.f;
  int deg = re - rs;
  float v = sum / (float)(deg > 0 ? deg : 1) + r + bv;
  float mx = act ? v : -1e30f;
  for (int o = 32; o > 0; o >>= 1) mx = fmaxf(mx, __shfl_xor(mx, o));
  float ex = act ? __expf(v - mx) : 0.f;
  float sm = ex;
  for (int o = 32; o > 0; o >>= 1) sm += __shfl_xor(sm, o);
  float ls = v - mx - __logf(sm);
  if (act) out[(size_t)node * NC + lane] = ls;
}

extern "C" void kernel_launch(void* const* d_in, const int* in_sizes, int n_in,
                              void* d_out, int out_size, void* d_ws, size_t ws_size,
                              hipStream_t stream) {
  const float* x   = (const float*)d_in[0];
  const int*   ei  = (const int*)d_in[1];
  const float* w1l = (const float*)d_in[2];
  const float* b1  = (const float*)d_in[3];
  const float* w1r = (const float*)d_in[4];
  const float* w2l = (const float*)d_in[5];
  const float* b2  = (const float*)d_in[6];
  const float* w2r = (const float*)d_in[7];
  float* out = (float*)d_out;
  const int* src = ei;
  const int* dst = ei + NE;

  char* ws = (char*)d_ws;
  size_t off = 0;
  auto alloc = [&](size_t bytes) -> char* {
    char* p = ws + off;
    off = (off + bytes + 255) & ~(size_t)255;
    return p;
  };
  int* bcnt     = (int*)alloc((size_t)(NBKT + 1) * 4);
  int* boff     = (int*)alloc((size_t)(NBKT + 1) * 4);
  int* bcur     = (int*)alloc((size_t)NBKT * 4);
  int* row_ptr  = (int*)alloc((size_t)(NN + 1) * 4);
  unsigned* pairs = (unsigned*)alloc((size_t)NE * 4);
  int* csr      = (int*)alloc((size_t)NE * 4);
  unsigned short* Wc  = (unsigned short*)alloc(256 * 256 * 2);
  unsigned short* W2c = (unsigned short*)alloc(80 * 256 * 2);
  unsigned*       xb  = (unsigned*)alloc((size_t)NN * 64 * 4);
  unsigned*       A1  = (unsigned*)alloc((size_t)NN * 128 * 4);
  unsigned short* H   = (unsigned short*)alloc((size_t)NN * 256 * 2);
  unsigned short* Pb  = (unsigned short*)alloc((size_t)NN * NC * 2);
  float*          R   = (float*)alloc((size_t)NN * NC * 4);

  hipMemsetAsync(bcnt, 0, (size_t)(NBKT + 1) * 4, stream);
  k_bhist<<<NBIN_BLOCKS, 256, 0, stream>>>(dst, bcnt);
  k_xbf16<<<(NN * 64 + 255) / 256, 256, 0, stream>>>(x, xb);
  k_bscan<<<1, 512, 0, stream>>>(bcnt, boff, bcur);
  k_bin<<<NBIN_BLOCKS, 256, 0, stream>>>(src, dst, bcur, pairs);
  k_csr<<<NBKT, 256, 0, stream>>>(pairs, boff, row_ptr, csr);
  k_packw<<<336, 256, 0, stream>>>(w1l, w1r, w2l, w2r, Wc, W2c);
  k_agg1<<<(NN + 3) / 4, 256, 0, stream>>>(xb, row_ptr, csr, A1);
  dim3 g1((NN + 127) / 128, 2);
  k_gemm1<<<g1, 256, 0, stream>>>((const unsigned short*)A1, Wc, b1, H);
  k_gemm2<<<(NN + 127) / 128, 256, 0, stream>>>(H, W2c, Pb, R);
  k_final<<<(NN + 3) / 4, 256, 0, stream>>>(Pb, R, row_ptr, csr, b2, out);
}

// Round 5
// 376.085 us; speedup vs baseline: 1.9553x; 1.1120x over previous
//
#include <hip/hip_runtime.h>
#include <hip/hip_bf16.h>
#include <stdint.h>

#define NN 100000
#define NE 1600000
#define DF 128
#define DH 256
#define NC 40
#define BSHIFT 8
#define NBKT 391          // ceil(NN/256) buckets, bucket = dst>>8
#define EPB 8192          // edges per k_bin block
#define NBIN_BLOCKS ((NE + EPB - 1) / EPB)   // 196

typedef __attribute__((ext_vector_type(8))) short short8;
typedef __attribute__((ext_vector_type(4))) float f32x4;

typedef const __attribute__((address_space(1))) unsigned int* gas1;
typedef __attribute__((address_space(3))) unsigned int* las3;

__device__ __forceinline__ void gload16(const void* g, void* l) {
  __builtin_amdgcn_global_load_lds((gas1)g, (las3)l, 16, 0, 0);
}

__device__ __forceinline__ unsigned short f2bf(float f) {
  union { float f; unsigned u; } v; v.f = f;
  unsigned r = v.u + 0x7FFFu + ((v.u >> 16) & 1u);
  return (unsigned short)(r >> 16);
}
__device__ __forceinline__ float bflo(unsigned u) {
  union { unsigned u; float f; } v; v.u = u << 16; return v.f;
}
__device__ __forceinline__ float bfhi(unsigned u) {
  union { unsigned u; float f; } v; v.u = u & 0xFFFF0000u; return v.f;
}

// ---------------- x -> bf16 pre-convert ----------------
__global__ void k_xbf16(const float* __restrict__ x, unsigned* __restrict__ xb) {
  int i = blockIdx.x * blockDim.x + threadIdx.x;
  if (i < NN * 64) {
    float2 v = ((const float2*)x)[i];
    xb[i] = ((unsigned)f2bf(v.y) << 16) | f2bf(v.x);
  }
}

// ---------------- CSR build: bucket counting sort ----------------
__global__ __launch_bounds__(256) void k_bhist(const int* __restrict__ dst, int* __restrict__ bcnt) {
  __shared__ int h[NBKT];
  int tid = threadIdx.x;
  for (int b = tid; b < NBKT; b += 256) h[b] = 0;
  __syncthreads();
  int base = blockIdx.x * EPB;
  int n = NE - base; if (n > EPB) n = EPB;
  for (int i = tid; i < n; i += 256) atomicAdd(&h[dst[base + i] >> BSHIFT], 1);
  __syncthreads();
  for (int b = tid; b < NBKT; b += 256) if (h[b]) atomicAdd(&bcnt[b], h[b]);
}

__global__ __launch_bounds__(512) void k_bscan(const int* __restrict__ bcnt,
                                               int* __restrict__ boff, int* __restrict__ bcur) {
  __shared__ int s[512];
  int tid = threadIdx.x;
  int v = (tid < NBKT) ? bcnt[tid] : 0;
  s[tid] = v;
  __syncthreads();
  for (int off = 1; off < 512; off <<= 1) {
    int a = (tid >= off) ? s[tid - off] : 0;
    __syncthreads();
    s[tid] += a;
    __syncthreads();
  }
  int excl = s[tid] - v;
  if (tid < NBKT) { boff[tid] = excl; bcur[tid] = excl; }
  if (tid == 0) boff[NBKT] = s[511];
}

__global__ __launch_bounds__(256) void k_bin(const int* __restrict__ src, const int* __restrict__ dst,
                                             int* __restrict__ bcur, unsigned* __restrict__ pairs) {
  __shared__ int hcnt[NBKT];
  __shared__ int hbase[NBKT];
  int tid = threadIdx.x;
  for (int b = tid; b < NBKT; b += 256) hcnt[b] = 0;
  __syncthreads();
  int base = blockIdx.x * EPB;
  int n = NE - base; if (n > EPB) n = EPB;
  for (int i = tid; i < n; i += 256) atomicAdd(&hcnt[dst[base + i] >> BSHIFT], 1);
  __syncthreads();
  for (int b = tid; b < NBKT; b += 256) hbase[b] = hcnt[b] ? atomicAdd(&bcur[b], hcnt[b]) : 0;
  __syncthreads();
  for (int b = tid; b < NBKT; b += 256) hcnt[b] = 0;
  __syncthreads();
  for (int i = tid; i < n; i += 256) {
    int s = src[base + i], d = dst[base + i];
    int b = d >> BSHIFT;
    int slot = atomicAdd(&hcnt[b], 1);
    pairs[hbase[b] + slot] = (unsigned)s | ((unsigned)(d & 255) << 17);
  }
}

__global__ __launch_bounds__(256) void k_csr(const unsigned* __restrict__ pairs,
                                             const int* __restrict__ boff,
                                             int* __restrict__ row_ptr, int* __restrict__ csr) {
  __shared__ int ncnt[256];
  __shared__ int noff[256];
  int tid = threadIdx.x;
  int b = blockIdx.x;
  int base = boff[b], end = boff[b + 1];
  ncnt[tid] = 0;
  __syncthreads();
  for (int e = base + tid; e < end; e += 256) atomicAdd(&ncnt[pairs[e] >> 17], 1);
  __syncthreads();
  int v = ncnt[tid];
  noff[tid] = v;
  __syncthreads();
  for (int off = 1; off < 256; off <<= 1) {
    int a = (tid >= off) ? noff[tid - off] : 0;
    __syncthreads();
    noff[tid] += a;
    __syncthreads();
  }
  int excl = noff[tid] - v;
  __syncthreads();
  noff[tid] = excl;
  ncnt[tid] = 0;
  __syncthreads();
  int gnode = (b << BSHIFT) + tid;
  if (gnode < NN) row_ptr[gnode] = base + excl;
  if (b == NBKT - 1 && tid == 0) row_ptr[NN] = NE;
  for (int e = base + tid; e < end; e += 256) {
    unsigned p = pairs[e];
    int ld = p >> 17;
    int slot = atomicAdd(&ncnt[ld], 1);
    csr[base + noff[ld] + slot] = (int)(p & 0x1FFFFu);
  }
}

// ---------------- weight pack (f32 -> bf16, concat) ----------------
__global__ void k_packw(const float* __restrict__ w1l, const float* __restrict__ w1r,
                        const float* __restrict__ w2l, const float* __restrict__ w2r,
                        unsigned short* __restrict__ Wc, unsigned short* __restrict__ W2c) {
  int i = blockIdx.x * blockDim.x + threadIdx.x;
  if (i < 256 * 256) {
    int o = i >> 8, k = i & 255;
    float v = (k < 128) ? w1l[o * 128 + k] : w1r[o * 128 + (k - 128)];
    Wc[i] = f2bf(v);
  }
  int j = i - 256 * 256;
  if (j >= 0 && j < 80 * 256) {
    int o = j >> 8, k = j & 255;
    float v = (o < 40) ? w2l[o * 256 + k] : w2r[(o - 40) * 256 + k];
    W2c[j] = f2bf(v);
  }
}

// ---------------- layer-1 aggregation: A1 = [mean-agg(xb) | xb] in bf16 ----------------
__global__ void k_agg1(const unsigned* __restrict__ xb, const int* __restrict__ row_ptr,
                       const int* __restrict__ csr_src, unsigned* __restrict__ A1) {
  int w = threadIdx.x >> 6, lane = threadIdx.x & 63;
  int node = blockIdx.x * 4 + w;
  if (node >= NN) return;
  int rs = row_ptr[node], re = row_ptr[node + 1];
  float a0 = 0.f, a1 = 0.f;
  int e = rs;
  for (; e + 7 < re; e += 8) {
    int si[8];
#pragma unroll
    for (int j = 0; j < 8; ++j) si[j] = csr_src[e + j];
    unsigned v[8];
#pragma unroll
    for (int j = 0; j < 8; ++j) v[j] = xb[(size_t)si[j] * 64 + lane];
#pragma unroll
    for (int j = 0; j < 8; ++j) { a0 += bflo(v[j]); a1 += bfhi(v[j]); }
  }
  for (; e < re; ++e) {
    unsigned v0 = xb[(size_t)csr_src[e] * 64 + lane];
    a0 += bflo(v0); a1 += bfhi(v0);
  }
  int deg = re - rs;
  float inv = 1.f / (float)(deg > 0 ? deg : 1);
  unsigned pack = ((unsigned)f2bf(a1 * inv) << 16) | f2bf(a0 * inv);
  A1[(size_t)node * 128 + lane] = pack;
  A1[(size_t)node * 128 + 64 + lane] = xb[(size_t)node * 64 + lane];
}

// ---------------- GEMM1: H = relu(A1 @ Wc^T + b1), bf16 in/out, f32 acc ----------------
__global__ __launch_bounds__(256) void k_gemm1(const unsigned short* __restrict__ A1,
                                               const unsigned short* __restrict__ Wc,
                                               const float* __restrict__ b1,
                                               unsigned short* __restrict__ H) {
  __shared__ __align__(16) unsigned short sA[128 * 64];
  __shared__ __align__(16) unsigned short sB[128 * 64];
  int tid = threadIdx.x;
  int w = tid >> 6, lane = tid & 63;
  int brow = blockIdx.x * 128;
  int bcol = blockIdx.y * 128;
  int wr = (w >> 1) * 64, wc = (w & 1) * 64;
  f32x4 acc[4][4] = {};

  for (int kt = 0; kt < 4; ++kt) {
#pragma unroll
    for (int t = 0; t < 4; ++t) {
      int c = (t * 4 + w) * 64 + lane;
      int r = c >> 3, cc = c & 7;
      int scc = cc ^ (r & 7);
      int gr = brow + r; if (gr > NN - 1) gr = NN - 1;
      gload16(A1 + (size_t)gr * 256 + kt * 64 + scc * 8, sA + c * 8);
    }
#pragma unroll
    for (int t = 0; t < 4; ++t) {
      int c = (t * 4 + w) * 64 + lane;
      int r = c >> 3, cc = c & 7;
      int scc = cc ^ (r & 7);
      gload16(Wc + (size_t)(bcol + r) * 256 + kt * 64 + scc * 8, sB + c * 8);
    }
    __syncthreads();
#pragma unroll
    for (int kg = 0; kg < 2; ++kg) {
      short8 af[4], bfr[4];
#pragma unroll
      for (int m = 0; m < 4; ++m) {
        int row = wr + m * 16 + (lane & 15);
        int cch = (kg * 4 + (lane >> 4)) ^ (row & 7);
        af[m] = *(const short8*)(sA + row * 64 + cch * 8);
      }
#pragma unroll
      for (int n = 0; n < 4; ++n) {
        int row = wc + n * 16 + (lane & 15);
        int cch = (kg * 4 + (lane >> 4)) ^ (row & 7);
        bfr[n] = *(const short8*)(sB + row * 64 + cch * 8);
      }
#pragma unroll
      for (int m = 0; m < 4; ++m)
#pragma unroll
        for (int n = 0; n < 4; ++n)
          acc[m][n] = __builtin_amdgcn_mfma_f32_16x16x32_bf16(af[m], bfr[n], acc[m][n], 0, 0, 0);
    }
    __syncthreads();
  }

  int colbase = bcol + wc + (lane & 15);
  int rowbase = brow + wr + (lane >> 4) * 4;
#pragma unroll
  for (int n = 0; n < 4; ++n) {
    int col = colbase + n * 16;
    float bias = b1[col];
#pragma unroll
    for (int m = 0; m < 4; ++m) {
      int row0 = rowbase + m * 16;
#pragma unroll
      for (int q = 0; q < 4; ++q) {
        int row = row0 + q;
        if (row < NN) {
          float v = acc[m][n][q] + bias;
          v = v > 0.f ? v : 0.f;
          H[(size_t)row * 256 + col] = f2bf(v);
        }
      }
    }
  }
}

// ---------------- GEMM2: [p|r] = H @ W2c^T ; p -> bf16 (stride 64, zero-pad), r -> f32 ----------------
__global__ __launch_bounds__(256) void k_gemm2(const unsigned short* __restrict__ H,
                                               const unsigned short* __restrict__ W2c,
                                               unsigned short* __restrict__ Pb,
                                               float* __restrict__ R) {
  __shared__ __align__(16) unsigned short sA[128 * 64];
  __shared__ __align__(16) unsigned short sB[80 * 64];
  int tid = threadIdx.x;
  int w = tid >> 6, lane = tid & 63;
  int brow = blockIdx.x * 128;
  f32x4 acc[2][5] = {};

  for (int kt = 0; kt < 4; ++kt) {
#pragma unroll
    for (int t = 0; t < 4; ++t) {
      int c = (t * 4 + w) * 64 + lane;
      int r = c >> 3, cc = c & 7;
      int scc = cc ^ (r & 7);
      int gr = brow + r; if (gr > NN - 1) gr = NN - 1;
      gload16(H + (size_t)gr * 256 + kt * 64 + scc * 8, sA + c * 8);
    }
    for (int g = w; g < 10; g += 4) {
      int c = g * 64 + lane;
      int r = c >> 3, cc = c & 7;
      int scc = cc ^ (r & 7);
      gload16(W2c + (size_t)r * 256 + kt * 64 + scc * 8, sB + c * 8);
    }
    __syncthreads();
#pragma unroll
    for (int kg = 0; kg < 2; ++kg) {
      short8 af[2], bfr[5];
#pragma unroll
      for (int m = 0; m < 2; ++m) {
        int row = w * 32 + m * 16 + (lane & 15);
        int cch = (kg * 4 + (lane >> 4)) ^ (row & 7);
        af[m] = *(const short8*)(sA + row * 64 + cch * 8);
      }
#pragma unroll
      for (int n = 0; n < 5; ++n) {
        int row = n * 16 + (lane & 15);
        int cch = (kg * 4 + (lane >> 4)) ^ (row & 7);
        bfr[n] = *(const short8*)(sB + row * 64 + cch * 8);
      }
#pragma unroll
      for (int m = 0; m < 2; ++m)
#pragma unroll
        for (int n = 0; n < 5; ++n)
          acc[m][n] = __builtin_amdgcn_mfma_f32_16x16x32_bf16(af[m], bfr[n], acc[m][n], 0, 0, 0);
    }
    __syncthreads();
  }

  int colbase = lane & 15;
  int rowbase = brow + w * 32 + (lane >> 4) * 4;
#pragma unroll
  for (int m = 0; m < 2; ++m) {
#pragma unroll
    for (int n = 0; n < 5; ++n) {
      int col = colbase + n * 16;
#pragma unroll
      for (int q = 0; q < 4; ++q) {
        int row = rowbase + m * 16 + q;
        if (row < NN) {
          float v = acc[m][n][q];
          if (col < NC) Pb[(size_t)row * 64 + col] = f2bf(v);
          else {
            R[(size_t)row * NC + (col - NC)] = v;
            if (col < 64) Pb[(size_t)row * 64 + col] = 0;  // zero the pad lanes
          }
        }
      }
    }
  }
}

// ---------------- final: out = log_softmax(mean-agg(p) + b2 + r) ----------------
// wave = 4 edge-groups x 16 lanes; each lane loads 8B (4 bf16 classes) per edge
__global__ __launch_bounds__(256) void k_final(const unsigned short* __restrict__ Pb,
                                               const float* __restrict__ R,
                                               const int* __restrict__ row_ptr,
                                               const int* __restrict__ csr_src,
                                               const float* __restrict__ b2,
                                               float* __restrict__ out) {
  int w = threadIdx.x >> 6, lane = threadIdx.x & 63;
  int g = lane >> 4, r = lane & 15;
  int node = blockIdx.x * 4 + w;
  if (node >= NN) return;
  int rs = row_ptr[node], re = row_ptr[node + 1];
  float s0 = 0.f, s1 = 0.f, s2 = 0.f, s3 = 0.f;
  int nfull = (re - rs) >> 3;
  int e = rs + g;
  for (int it = 0; it < nfull; ++it, e += 8) {
    int sa = csr_src[e];
    int sb = csr_src[e + 4];
    uint2 va = *(const uint2*)(Pb + (size_t)sa * 64 + r * 4);
    uint2 vb = *(const uint2*)(Pb + (size_t)sb * 64 + r * 4);
    s0 += bflo(va.x) + bflo(vb.x);
    s1 += bfhi(va.x) + bfhi(vb.x);
    s2 += bflo(va.y) + bflo(vb.y);
    s3 += bfhi(va.y) + bfhi(vb.y);
  }
  if (e < re) {
    int sa = csr_src[e];
    uint2 va = *(const uint2*)(Pb + (size_t)sa * 64 + r * 4);
    s0 += bflo(va.x); s1 += bfhi(va.x); s2 += bflo(va.y); s3 += bfhi(va.y);
  }
  e += 4;
  if (e < re) {
    int sa = csr_src[e];
    uint2 va = *(const uint2*)(Pb + (size_t)sa * 64 + r * 4);
    s0 += bflo(va.x); s1 += bfhi(va.x); s2 += bflo(va.y); s3 += bfhi(va.y);
  }
  // combine the 4 edge-groups
  s0 += __shfl_xor(s0, 16); s0 += __shfl_xor(s0, 32);
  s1 += __shfl_xor(s1, 16); s1 += __shfl_xor(s1, 32);
  s2 += __shfl_xor(s2, 16); s2 += __shfl_xor(s2, 32);
  s3 += __shfl_xor(s3, 16); s3 += __shfl_xor(s3, 32);

  int deg = re - rs;
  float inv = 1.f / (float)(deg > 0 ? deg : 1);
  bool act = r < 10;   // lane r holds classes 4r..4r+3; valid for 4r < 40
  float4 rr = act ? *(const float4*)(R + (size_t)node * NC + r * 4) : make_float4(0, 0, 0, 0);
  float4 bb = act ? *(const float4*)(b2 + r * 4) : make_float4(0, 0, 0, 0);
  float v0 = s0 * inv + rr.x + bb.x;
  float v1 = s1 * inv + rr.y + bb.y;
  float v2 = s2 * inv + rr.z + bb.z;
  float v3 = s3 * inv + rr.w + bb.w;
  float mx = act ? fmaxf(fmaxf(v0, v1), fmaxf(v2, v3)) : -1e30f;
#pragma unroll
  for (int o = 1; o < 16; o <<= 1) mx = fmaxf(mx, __shfl_xor(mx, o));
  float ex = act ? (__expf(v0 - mx) + __expf(v1 - mx) + __expf(v2 - mx) + __expf(v3 - mx)) : 0.f;
#pragma unroll
  for (int o = 1; o < 16; o <<= 1) ex += __shfl_xor(ex, o);
  float ls = mx + __logf(ex);
  if (g == 0 && act) {
    float4 o4 = make_float4(v0 - ls, v1 - ls, v2 - ls, v3 - ls);
    *(float4*)(out + (size_t)node * NC + r * 4) = o4;
  }
}

extern "C" void kernel_launch(void* const* d_in, const int* in_sizes, int n_in,
                              void* d_out, int out_size, void* d_ws, size_t ws_size,
                              hipStream_t stream) {
  const float* x   = (const float*)d_in[0];
  const int*   ei  = (const int*)d_in[1];
  const float* w1l = (const float*)d_in[2];
  const float* b1  = (const float*)d_in[3];
  const float* w1r = (const float*)d_in[4];
  const float* w2l = (const float*)d_in[5];
  const float* b2  = (const float*)d_in[6];
  const float* w2r = (const float*)d_in[7];
  float* out = (float*)d_out;
  const int* src = ei;
  const int* dst = ei + NE;

  char* ws = (char*)d_ws;
  size_t off = 0;
  auto alloc = [&](size_t bytes) -> char* {
    char* p = ws + off;
    off = (off + bytes + 255) & ~(size_t)255;
    return p;
  };
  int* bcnt     = (int*)alloc((size_t)(NBKT + 1) * 4);
  int* boff     = (int*)alloc((size_t)(NBKT + 1) * 4);
  int* bcur     = (int*)alloc((size_t)NBKT * 4);
  int* row_ptr  = (int*)alloc((size_t)(NN + 1) * 4);
  unsigned* pairs = (unsigned*)alloc((size_t)NE * 4);
  int* csr      = (int*)alloc((size_t)NE * 4);
  unsigned short* Wc  = (unsigned short*)alloc(256 * 256 * 2);
  unsigned short* W2c = (unsigned short*)alloc(80 * 256 * 2);
  unsigned*       xb  = (unsigned*)alloc((size_t)NN * 64 * 4);
  unsigned*       A1  = (unsigned*)alloc((size_t)NN * 128 * 4);
  unsigned short* H   = (unsigned short*)alloc((size_t)NN * 256 * 2);
  unsigned short* Pb  = (unsigned short*)alloc((size_t)NN * 64 * 2);   // padded to 64 classes
  float*          R   = (float*)alloc((size_t)NN * NC * 4);

  hipMemsetAsync(bcnt, 0, (size_t)(NBKT + 1) * 4, stream);
  k_bhist<<<NBIN_BLOCKS, 256, 0, stream>>>(dst, bcnt);
  k_xbf16<<<(NN * 64 + 255) / 256, 256, 0, stream>>>(x, xb);
  k_bscan<<<1, 512, 0, stream>>>(bcnt, boff, bcur);
  k_bin<<<NBIN_BLOCKS, 256, 0, stream>>>(src, dst, bcur, pairs);
  k_csr<<<NBKT, 256, 0, stream>>>(pairs, boff, row_ptr, csr);
  k_packw<<<336, 256, 0, stream>>>(w1l, w1r, w2l, w2r, Wc, W2c);
  k_agg1<<<(NN + 3) / 4, 256, 0, stream>>>(xb, row_ptr, csr, A1);
  dim3 g1((NN + 127) / 128, 2);
  k_gemm1<<<g1, 256, 0, stream>>>((const unsigned short*)A1, Wc, b1, H);
  k_gemm2<<<(NN + 127) / 128, 256, 0, stream>>>(H, W2c, Pb, R);
  k_final<<<(NN + 3) / 4, 256, 0, stream>>>(Pb, R, row_ptr, csr, b2, out);
}

// Round 6
// 362.316 us; speedup vs baseline: 2.0297x; 1.0380x over previous
//
#include <hip/hip_runtime.h>
#include <hip/hip_bf16.h>
#include <stdint.h>

#define NN 100000
#define NE 1600000
#define DF 128
#define DH 256
#define NC 40
#define BSHIFT 8
#define NBKT 391          // ceil(NN/256) buckets, bucket = dst>>8
#define EPB 8192          // edges per k_bin block
#define NBIN_BLOCKS ((NE + EPB - 1) / EPB)   // 196

typedef __attribute__((ext_vector_type(8))) short short8;
typedef __attribute__((ext_vector_type(4))) float f32x4;

typedef const __attribute__((address_space(1))) unsigned int* gas1;
typedef __attribute__((address_space(3))) unsigned int* las3;

__device__ __forceinline__ void gload16(const void* g, void* l) {
  __builtin_amdgcn_global_load_lds((gas1)g, (las3)l, 16, 0, 0);
}

__device__ __forceinline__ unsigned short f2bf(float f) {
  union { float f; unsigned u; } v; v.f = f;
  unsigned r = v.u + 0x7FFFu + ((v.u >> 16) & 1u);
  return (unsigned short)(r >> 16);
}
__device__ __forceinline__ float bflo(unsigned u) {
  union { unsigned u; float f; } v; v.u = u << 16; return v.f;
}
__device__ __forceinline__ float bfhi(unsigned u) {
  union { unsigned u; float f; } v; v.u = u & 0xFFFF0000u; return v.f;
}

// ---------------- x -> bf16 pre-convert ----------------
__global__ void k_xbf16(const float* __restrict__ x, unsigned* __restrict__ xb) {
  int i = blockIdx.x * blockDim.x + threadIdx.x;
  if (i < NN * 64) {
    float2 v = ((const float2*)x)[i];
    xb[i] = ((unsigned)f2bf(v.y) << 16) | f2bf(v.x);
  }
}

// ---------------- CSR build: bucket counting sort ----------------
__global__ __launch_bounds__(256) void k_bhist(const int* __restrict__ dst, int* __restrict__ bcnt) {
  __shared__ int h[NBKT];
  int tid = threadIdx.x;
  for (int b = tid; b < NBKT; b += 256) h[b] = 0;
  __syncthreads();
  int base = blockIdx.x * EPB;
  int n = NE - base; if (n > EPB) n = EPB;
  for (int i = tid; i < n; i += 256) atomicAdd(&h[dst[base + i] >> BSHIFT], 1);
  __syncthreads();
  for (int b = tid; b < NBKT; b += 256) if (h[b]) atomicAdd(&bcnt[b], h[b]);
}

__global__ __launch_bounds__(512) void k_bscan(const int* __restrict__ bcnt,
                                               int* __restrict__ boff, int* __restrict__ bcur) {
  __shared__ int s[512];
  int tid = threadIdx.x;
  int v = (tid < NBKT) ? bcnt[tid] : 0;
  s[tid] = v;
  __syncthreads();
  for (int off = 1; off < 512; off <<= 1) {
    int a = (tid >= off) ? s[tid - off] : 0;
    __syncthreads();
    s[tid] += a;
    __syncthreads();
  }
  int excl = s[tid] - v;
  if (tid < NBKT) { boff[tid] = excl; bcur[tid] = excl; }
  if (tid == 0) boff[NBKT] = s[511];
}

__global__ __launch_bounds__(256) void k_bin(const int* __restrict__ src, const int* __restrict__ dst,
                                             int* __restrict__ bcur, unsigned* __restrict__ pairs) {
  __shared__ int hcnt[NBKT];
  __shared__ int hbase[NBKT];
  int tid = threadIdx.x;
  for (int b = tid; b < NBKT; b += 256) hcnt[b] = 0;
  __syncthreads();
  int base = blockIdx.x * EPB;
  int n = NE - base; if (n > EPB) n = EPB;
  for (int i = tid; i < n; i += 256) atomicAdd(&hcnt[dst[base + i] >> BSHIFT], 1);
  __syncthreads();
  for (int b = tid; b < NBKT; b += 256) hbase[b] = hcnt[b] ? atomicAdd(&bcur[b], hcnt[b]) : 0;
  __syncthreads();
  for (int b = tid; b < NBKT; b += 256) hcnt[b] = 0;
  __syncthreads();
  for (int i = tid; i < n; i += 256) {
    int s = src[base + i], d = dst[base + i];
    int b = d >> BSHIFT;
    int slot = atomicAdd(&hcnt[b], 1);
    pairs[hbase[b] + slot] = (unsigned)s | ((unsigned)(d & 255) << 17);
  }
}

__global__ __launch_bounds__(256) void k_csr(const unsigned* __restrict__ pairs,
                                             const int* __restrict__ boff,
                                             int* __restrict__ row_ptr, int* __restrict__ csr) {
  __shared__ int ncnt[256];
  __shared__ int noff[256];
  int tid = threadIdx.x;
  int b = blockIdx.x;
  int base = boff[b], end = boff[b + 1];
  ncnt[tid] = 0;
  __syncthreads();
  for (int e = base + tid; e < end; e += 256) atomicAdd(&ncnt[pairs[e] >> 17], 1);
  __syncthreads();
  int v = ncnt[tid];
  noff[tid] = v;
  __syncthreads();
  for (int off = 1; off < 256; off <<= 1) {
    int a = (tid >= off) ? noff[tid - off] : 0;
    __syncthreads();
    noff[tid] += a;
    __syncthreads();
  }
  int excl = noff[tid] - v;
  __syncthreads();
  noff[tid] = excl;
  ncnt[tid] = 0;
  __syncthreads();
  int gnode = (b << BSHIFT) + tid;
  if (gnode < NN) row_ptr[gnode] = base + excl;
  if (b == NBKT - 1 && tid == 0) row_ptr[NN] = NE;
  for (int e = base + tid; e < end; e += 256) {
    unsigned p = pairs[e];
    int ld = p >> 17;
    int slot = atomicAdd(&ncnt[ld], 1);
    csr[base + noff[ld] + slot] = (int)(p & 0x1FFFFu);
  }
}

// ---------------- weight pack (f32 -> bf16, concat) ----------------
__global__ void k_packw(const float* __restrict__ w1l, const float* __restrict__ w1r,
                        const float* __restrict__ w2l, const float* __restrict__ w2r,
                        unsigned short* __restrict__ Wc, unsigned short* __restrict__ W2c) {
  int i = blockIdx.x * blockDim.x + threadIdx.x;
  if (i < 256 * 256) {
    int o = i >> 8, k = i & 255;
    float v = (k < 128) ? w1l[o * 128 + k] : w1r[o * 128 + (k - 128)];
    Wc[i] = f2bf(v);
  }
  int j = i - 256 * 256;
  if (j >= 0 && j < 80 * 256) {
    int o = j >> 8, k = j & 255;
    float v = (o < 40) ? w2l[o * 256 + k] : w2r[(o - 40) * 256 + k];
    W2c[j] = f2bf(v);
  }
}

// ---------------- layer-1 aggregation: A1 = mean-agg(xb) only (128-wide, bf16) ----------------
// every iteration is a masked 8-wide gather: no serial tail
__global__ void k_agg1(const unsigned* __restrict__ xb, const int* __restrict__ row_ptr,
                       const int* __restrict__ csr_src, unsigned* __restrict__ A1) {
  int w = threadIdx.x >> 6, lane = threadIdx.x & 63;
  int node = blockIdx.x * 4 + w;
  if (node >= NN) return;
  int rs = row_ptr[node], re = row_ptr[node + 1];
  float a0 = 0.f, a1 = 0.f;
  for (int e = rs; e < re; e += 8) {
    unsigned v[8];
#pragma unroll
    for (int j = 0; j < 8; ++j) {
      int ej = e + j;
      int idx = csr_src[ej < re ? ej : re - 1];   // wave-uniform clamp
      unsigned t = xb[(size_t)idx * 64 + lane];
      v[j] = (ej < re) ? t : 0u;                  // wave-uniform mask
    }
#pragma unroll
    for (int j = 0; j < 8; ++j) { a0 += bflo(v[j]); a1 += bfhi(v[j]); }
  }
  int deg = re - rs;
  float inv = 1.f / (float)(deg > 0 ? deg : 1);
  unsigned pack = ((unsigned)f2bf(a1 * inv) << 16) | f2bf(a0 * inv);
  A1[(size_t)node * 64 + lane] = pack;
}

// ---------------- GEMM1: H = relu([A1 | xb] @ Wc^T + b1), full-width 128x256 block ----------------
// 512 threads / 8 waves; wave (w>>1, w&1) computes 32 rows x 128 cols
__global__ __launch_bounds__(512) void k_gemm1(const unsigned short* __restrict__ A1,
                                               const unsigned short* __restrict__ XB,
                                               const unsigned short* __restrict__ Wc,
                                               const float* __restrict__ b1,
                                               unsigned short* __restrict__ H) {
  __shared__ __align__(16) unsigned short sA[128 * 64];
  __shared__ __align__(16) unsigned short sB[256 * 64];
  int tid = threadIdx.x;
  int w = tid >> 6, lane = tid & 63;
  int brow = blockIdx.x * 128;
  int wr = (w >> 1) * 32, wc = (w & 1) * 128;
  f32x4 acc[2][8] = {};

  for (int kt = 0; kt < 4; ++kt) {
    const unsigned short* srcA = (kt < 2) ? A1 : XB;
    int kcol = (kt & 1) * 64;
#pragma unroll
    for (int t = 0; t < 2; ++t) {
      int c = t * 512 + tid;          // 1024 chunks of 8 bf16
      int r = c >> 3, cc = c & 7;
      int scc = cc ^ (r & 7);
      int gr = brow + r; if (gr > NN - 1) gr = NN - 1;
      gload16(srcA + (size_t)gr * 128 + kcol + scc * 8, sA + c * 8);
    }
#pragma unroll
    for (int t = 0; t < 4; ++t) {
      int c = t * 512 + tid;          // 2048 chunks
      int r = c >> 3, cc = c & 7;
      int scc = cc ^ (r & 7);
      gload16(Wc + (size_t)r * 256 + kt * 64 + scc * 8, sB + c * 8);
    }
    __syncthreads();
#pragma unroll
    for (int kg = 0; kg < 2; ++kg) {
      short8 af[2], bfr[8];
#pragma unroll
      for (int m = 0; m < 2; ++m) {
        int row = wr + m * 16 + (lane & 15);
        int cch = (kg * 4 + (lane >> 4)) ^ (row & 7);
        af[m] = *(const short8*)(sA + row * 64 + cch * 8);
      }
#pragma unroll
      for (int n = 0; n < 8; ++n) {
        int row = wc + n * 16 + (lane & 15);
        int cch = (kg * 4 + (lane >> 4)) ^ (row & 7);
        bfr[n] = *(const short8*)(sB + row * 64 + cch * 8);
      }
#pragma unroll
      for (int m = 0; m < 2; ++m)
#pragma unroll
        for (int n = 0; n < 8; ++n)
          acc[m][n] = __builtin_amdgcn_mfma_f32_16x16x32_bf16(af[m], bfr[n], acc[m][n], 0, 0, 0);
    }
    __syncthreads();
  }

  int colbase = wc + (lane & 15);
  int rowbase = brow + wr + (lane >> 4) * 4;
#pragma unroll
  for (int n = 0; n < 8; ++n) {
    int col = colbase + n * 16;
    float bias = b1[col];
#pragma unroll
    for (int m = 0; m < 2; ++m) {
      int row0 = rowbase + m * 16;
#pragma unroll
      for (int q = 0; q < 4; ++q) {
        int row = row0 + q;
        if (row < NN) {
          float v = acc[m][n][q] + bias;
          v = v > 0.f ? v : 0.f;
          H[(size_t)row * 256 + col] = f2bf(v);
        }
      }
    }
  }
}

// ---------------- GEMM2: [p|r] = H @ W2c^T ; p -> bf16 (stride 64, zero-pad), r -> f32 ----------------
__global__ __launch_bounds__(256) void k_gemm2(const unsigned short* __restrict__ H,
                                               const unsigned short* __restrict__ W2c,
                                               unsigned short* __restrict__ Pb,
                                               float* __restrict__ R) {
  __shared__ __align__(16) unsigned short sA[128 * 64];
  __shared__ __align__(16) unsigned short sB[80 * 64];
  int tid = threadIdx.x;
  int w = tid >> 6, lane = tid & 63;
  int brow = blockIdx.x * 128;
  f32x4 acc[2][5] = {};

  for (int kt = 0; kt < 4; ++kt) {
#pragma unroll
    for (int t = 0; t < 4; ++t) {
      int c = (t * 4 + w) * 64 + lane;
      int r = c >> 3, cc = c & 7;
      int scc = cc ^ (r & 7);
      int gr = brow + r; if (gr > NN - 1) gr = NN - 1;
      gload16(H + (size_t)gr * 256 + kt * 64 + scc * 8, sA + c * 8);
    }
    for (int g = w; g < 10; g += 4) {
      int c = g * 64 + lane;
      int r = c >> 3, cc = c & 7;
      int scc = cc ^ (r & 7);
      gload16(W2c + (size_t)r * 256 + kt * 64 + scc * 8, sB + c * 8);
    }
    __syncthreads();
#pragma unroll
    for (int kg = 0; kg < 2; ++kg) {
      short8 af[2], bfr[5];
#pragma unroll
      for (int m = 0; m < 2; ++m) {
        int row = w * 32 + m * 16 + (lane & 15);
        int cch = (kg * 4 + (lane >> 4)) ^ (row & 7);
        af[m] = *(const short8*)(sA + row * 64 + cch * 8);
      }
#pragma unroll
      for (int n = 0; n < 5; ++n) {
        int row = n * 16 + (lane & 15);
        int cch = (kg * 4 + (lane >> 4)) ^ (row & 7);
        bfr[n] = *(const short8*)(sB + row * 64 + cch * 8);
      }
#pragma unroll
      for (int m = 0; m < 2; ++m)
#pragma unroll
        for (int n = 0; n < 5; ++n)
          acc[m][n] = __builtin_amdgcn_mfma_f32_16x16x32_bf16(af[m], bfr[n], acc[m][n], 0, 0, 0);
    }
    __syncthreads();
  }

  int colbase = lane & 15;
  int rowbase = brow + w * 32 + (lane >> 4) * 4;
#pragma unroll
  for (int m = 0; m < 2; ++m) {
#pragma unroll
    for (int n = 0; n < 5; ++n) {
      int col = colbase + n * 16;
#pragma unroll
      for (int q = 0; q < 4; ++q) {
        int row = rowbase + m * 16 + q;
        if (row < NN) {
          float v = acc[m][n][q];
          if (col < NC) Pb[(size_t)row * 64 + col] = f2bf(v);
          else {
            R[(size_t)row * NC + (col - NC)] = v;
            if (col < 64) Pb[(size_t)row * 64 + col] = 0;  // zero the pad lanes
          }
        }
      }
    }
  }
}

// ---------------- final: out = log_softmax(mean-agg(p) + b2 + r) ----------------
// wave = 4 edge-groups x 16 lanes; each lane loads 8B (4 bf16 classes) per edge
__global__ __launch_bounds__(256) void k_final(const unsigned short* __restrict__ Pb,
                                               const float* __restrict__ R,
                                               const int* __restrict__ row_ptr,
                                               const int* __restrict__ csr_src,
                                               const float* __restrict__ b2,
                                               float* __restrict__ out) {
  int w = threadIdx.x >> 6, lane = threadIdx.x & 63;
  int g = lane >> 4, r = lane & 15;
  int node = blockIdx.x * 4 + w;
  if (node >= NN) return;
  int rs = row_ptr[node], re = row_ptr[node + 1];
  float s0 = 0.f, s1 = 0.f, s2 = 0.f, s3 = 0.f;
  int nfull = (re - rs) >> 3;
  int e = rs + g;
  for (int it = 0; it < nfull; ++it, e += 8) {
    int sa = csr_src[e];
    int sb = csr_src[e + 4];
    uint2 va = *(const uint2*)(Pb + (size_t)sa * 64 + r * 4);
    uint2 vb = *(const uint2*)(Pb + (size_t)sb * 64 + r * 4);
    s0 += bflo(va.x) + bflo(vb.x);
    s1 += bfhi(va.x) + bfhi(vb.x);
    s2 += bflo(va.y) + bflo(vb.y);
    s3 += bfhi(va.y) + bfhi(vb.y);
  }
  if (e < re) {
    int sa = csr_src[e];
    uint2 va = *(const uint2*)(Pb + (size_t)sa * 64 + r * 4);
    s0 += bflo(va.x); s1 += bfhi(va.x); s2 += bflo(va.y); s3 += bfhi(va.y);
  }
  e += 4;
  if (e < re) {
    int sa = csr_src[e];
    uint2 va = *(const uint2*)(Pb + (size_t)sa * 64 + r * 4);
    s0 += bflo(va.x); s1 += bfhi(va.x); s2 += bflo(va.y); s3 += bfhi(va.y);
  }
  // combine the 4 edge-groups
  s0 += __shfl_xor(s0, 16); s0 += __shfl_xor(s0, 32);
  s1 += __shfl_xor(s1, 16); s1 += __shfl_xor(s1, 32);
  s2 += __shfl_xor(s2, 16); s2 += __shfl_xor(s2, 32);
  s3 += __shfl_xor(s3, 16); s3 += __shfl_xor(s3, 32);

  int deg = re - rs;
  float inv = 1.f / (float)(deg > 0 ? deg : 1);
  bool act = r < 10;   // lane r holds classes 4r..4r+3; valid for 4r < 40
  float4 rr = act ? *(const float4*)(R + (size_t)node * NC + r * 4) : make_float4(0, 0, 0, 0);
  float4 bb = act ? *(const float4*)(b2 + r * 4) : make_float4(0, 0, 0, 0);
  float v0 = s0 * inv + rr.x + bb.x;
  float v1 = s1 * inv + rr.y + bb.y;
  float v2 = s2 * inv + rr.z + bb.z;
  float v3 = s3 * inv + rr.w + bb.w;
  float mx = act ? fmaxf(fmaxf(v0, v1), fmaxf(v2, v3)) : -1e30f;
#pragma unroll
  for (int o = 1; o < 16; o <<= 1) mx = fmaxf(mx, __shfl_xor(mx, o));
  float ex = act ? (__expf(v0 - mx) + __expf(v1 - mx) + __expf(v2 - mx) + __expf(v3 - mx)) : 0.f;
#pragma unroll
  for (int o = 1; o < 16; o <<= 1) ex += __shfl_xor(ex, o);
  float ls = mx + __logf(ex);
  if (g == 0 && act) {
    float4 o4 = make_float4(v0 - ls, v1 - ls, v2 - ls, v3 - ls);
    *(float4*)(out + (size_t)node * NC + r * 4) = o4;
  }
}

extern "C" void kernel_launch(void* const* d_in, const int* in_sizes, int n_in,
                              void* d_out, int out_size, void* d_ws, size_t ws_size,
                              hipStream_t stream) {
  const float* x   = (const float*)d_in[0];
  const int*   ei  = (const int*)d_in[1];
  const float* w1l = (const float*)d_in[2];
  const float* b1  = (const float*)d_in[3];
  const float* w1r = (const float*)d_in[4];
  const float* w2l = (const float*)d_in[5];
  const float* b2  = (const float*)d_in[6];
  const float* w2r = (const float*)d_in[7];
  float* out = (float*)d_out;
  const int* src = ei;
  const int* dst = ei + NE;

  char* ws = (char*)d_ws;
  size_t off = 0;
  auto alloc = [&](size_t bytes) -> char* {
    char* p = ws + off;
    off = (off + bytes + 255) & ~(size_t)255;
    return p;
  };
  int* bcnt     = (int*)alloc((size_t)(NBKT + 1) * 4);
  int* boff     = (int*)alloc((size_t)(NBKT + 1) * 4);
  int* bcur     = (int*)alloc((size_t)NBKT * 4);
  int* row_ptr  = (int*)alloc((size_t)(NN + 1) * 4);
  unsigned* pairs = (unsigned*)alloc((size_t)NE * 4);
  int* csr      = (int*)alloc((size_t)NE * 4);
  unsigned short* Wc  = (unsigned short*)alloc(256 * 256 * 2);
  unsigned short* W2c = (unsigned short*)alloc(80 * 256 * 2);
  unsigned*       xb  = (unsigned*)alloc((size_t)NN * 64 * 4);
  unsigned*       A1  = (unsigned*)alloc((size_t)NN * 64 * 4);   // agg only, 128 bf16/row
  unsigned short* H   = (unsigned short*)alloc((size_t)NN * 256 * 2);
  unsigned short* Pb  = (unsigned short*)alloc((size_t)NN * 64 * 2);   // padded to 64 classes
  float*          R   = (float*)alloc((size_t)NN * NC * 4);

  hipMemsetAsync(bcnt, 0, (size_t)(NBKT + 1) * 4, stream);
  k_bhist<<<NBIN_BLOCKS, 256, 0, stream>>>(dst, bcnt);
  k_xbf16<<<(NN * 64 + 255) / 256, 256, 0, stream>>>(x, xb);
  k_bscan<<<1, 512, 0, stream>>>(bcnt, boff, bcur);
  k_bin<<<NBIN_BLOCKS, 256, 0, stream>>>(src, dst, bcur, pairs);
  k_csr<<<NBKT, 256, 0, stream>>>(pairs, boff, row_ptr, csr);
  k_packw<<<336, 256, 0, stream>>>(w1l, w1r, w2l, w2r, Wc, W2c);
  k_agg1<<<(NN + 3) / 4, 256, 0, stream>>>(xb, row_ptr, csr, A1);
  k_gemm1<<<(NN + 127) / 128, 512, 0, stream>>>((const unsigned short*)A1,
                                                (const unsigned short*)xb, Wc, b1, H);
  k_gemm2<<<(NN + 127) / 128, 256, 0, stream>>>(H, W2c, Pb, R);
  k_final<<<(NN + 3) / 4, 256, 0, stream>>>(Pb, R, row_ptr, csr, b2, out);
}

// Round 7
// 323.350 us; speedup vs baseline: 2.2742x; 1.1205x over previous
//
#include <hip/hip_runtime.h>
#include <hip/hip_bf16.h>
#include <stdint.h>

#define NN 100000
#define NE 1600000
#define DF 128
#define DH 256
#define NC 40
#define BSHIFT 8
#define NBKT 391          // ceil(NN/256) buckets, bucket = dst>>8
#define EPB 8192          // edges per k_bin block
#define NBIN_BLOCKS ((NE + EPB - 1) / EPB)   // 196

typedef __attribute__((ext_vector_type(8))) short short8;
typedef __attribute__((ext_vector_type(4))) float f32x4;

typedef const __attribute__((address_space(1))) unsigned int* gas1;
typedef __attribute__((address_space(3))) unsigned int* las3;

__device__ __forceinline__ void gload16(const void* g, void* l) {
  __builtin_amdgcn_global_load_lds((gas1)g, (las3)l, 16, 0, 0);
}

__device__ __forceinline__ unsigned short f2bf(float f) {
  union { float f; unsigned u; } v; v.f = f;
  unsigned r = v.u + 0x7FFFu + ((v.u >> 16) & 1u);
  return (unsigned short)(r >> 16);
}
__device__ __forceinline__ float bflo(unsigned u) {
  union { unsigned u; float f; } v; v.u = u << 16; return v.f;
}
__device__ __forceinline__ float bfhi(unsigned u) {
  union { unsigned u; float f; } v; v.u = u & 0xFFFF0000u; return v.f;
}

// ---------------- x -> bf16 pre-convert ----------------
__global__ void k_xbf16(const float* __restrict__ x, unsigned* __restrict__ xb) {
  int i = blockIdx.x * blockDim.x + threadIdx.x;
  if (i < NN * 64) {
    float2 v = ((const float2*)x)[i];
    xb[i] = ((unsigned)f2bf(v.y) << 16) | f2bf(v.x);
  }
}

// ---------------- CSR build: bucket counting sort ----------------
__global__ __launch_bounds__(256) void k_bhist(const int* __restrict__ dst, int* __restrict__ bcnt) {
  __shared__ int h[NBKT];
  int tid = threadIdx.x;
  for (int b = tid; b < NBKT; b += 256) h[b] = 0;
  __syncthreads();
  int base = blockIdx.x * EPB;
  int n = NE - base; if (n > EPB) n = EPB;
  for (int i = tid; i < n; i += 256) atomicAdd(&h[dst[base + i] >> BSHIFT], 1);
  __syncthreads();
  for (int b = tid; b < NBKT; b += 256) if (h[b]) atomicAdd(&bcnt[b], h[b]);
}

__global__ __launch_bounds__(512) void k_bscan(const int* __restrict__ bcnt,
                                               int* __restrict__ boff, int* __restrict__ bcur) {
  __shared__ int s[512];
  int tid = threadIdx.x;
  int v = (tid < NBKT) ? bcnt[tid] : 0;
  s[tid] = v;
  __syncthreads();
  for (int off = 1; off < 512; off <<= 1) {
    int a = (tid >= off) ? s[tid - off] : 0;
    __syncthreads();
    s[tid] += a;
    __syncthreads();
  }
  int excl = s[tid] - v;
  if (tid < NBKT) { boff[tid] = excl; bcur[tid] = excl; }
  if (tid == 0) boff[NBKT] = s[511];
}

__global__ __launch_bounds__(256) void k_bin(const int* __restrict__ src, const int* __restrict__ dst,
                                             int* __restrict__ bcur, unsigned* __restrict__ pairs) {
  __shared__ int hcnt[NBKT];
  __shared__ int hbase[NBKT];
  int tid = threadIdx.x;
  for (int b = tid; b < NBKT; b += 256) hcnt[b] = 0;
  __syncthreads();
  int base = blockIdx.x * EPB;
  int n = NE - base; if (n > EPB) n = EPB;
  for (int i = tid; i < n; i += 256) atomicAdd(&hcnt[dst[base + i] >> BSHIFT], 1);
  __syncthreads();
  for (int b = tid; b < NBKT; b += 256) hbase[b] = hcnt[b] ? atomicAdd(&bcur[b], hcnt[b]) : 0;
  __syncthreads();
  for (int b = tid; b < NBKT; b += 256) hcnt[b] = 0;
  __syncthreads();
  for (int i = tid; i < n; i += 256) {
    int s = src[base + i], d = dst[base + i];
    int b = d >> BSHIFT;
    int slot = atomicAdd(&hcnt[b], 1);
    pairs[hbase[b] + slot] = (unsigned)s | ((unsigned)(d & 255) << 17);
  }
}

__global__ __launch_bounds__(256) void k_csr(const unsigned* __restrict__ pairs,
                                             const int* __restrict__ boff,
                                             int* __restrict__ row_ptr, int* __restrict__ csr) {
  __shared__ int ncnt[256];
  __shared__ int noff[256];
  int tid = threadIdx.x;
  int b = blockIdx.x;
  int base = boff[b], end = boff[b + 1];
  ncnt[tid] = 0;
  __syncthreads();
  for (int e = base + tid; e < end; e += 256) atomicAdd(&ncnt[pairs[e] >> 17], 1);
  __syncthreads();
  int v = ncnt[tid];
  noff[tid] = v;
  __syncthreads();
  for (int off = 1; off < 256; off <<= 1) {
    int a = (tid >= off) ? noff[tid - off] : 0;
    __syncthreads();
    noff[tid] += a;
    __syncthreads();
  }
  int excl = noff[tid] - v;
  __syncthreads();
  noff[tid] = excl;
  ncnt[tid] = 0;
  __syncthreads();
  int gnode = (b << BSHIFT) + tid;
  if (gnode < NN) row_ptr[gnode] = base + excl;
  if (b == NBKT - 1 && tid == 0) row_ptr[NN] = NE;
  for (int e = base + tid; e < end; e += 256) {
    unsigned p = pairs[e];
    int ld = p >> 17;
    int slot = atomicAdd(&ncnt[ld], 1);
    csr[base + noff[ld] + slot] = (int)(p & 0x1FFFFu);
  }
}

// ---------------- weight pack (f32 -> bf16, concat) ----------------
__global__ void k_packw(const float* __restrict__ w1l, const float* __restrict__ w1r,
                        const float* __restrict__ w2l, const float* __restrict__ w2r,
                        unsigned short* __restrict__ Wc, unsigned short* __restrict__ W2c) {
  int i = blockIdx.x * blockDim.x + threadIdx.x;
  if (i < 256 * 256) {
    int o = i >> 8, k = i & 255;
    float v = (k < 128) ? w1l[o * 128 + k] : w1r[o * 128 + (k - 128)];
    Wc[i] = f2bf(v);
  }
  int j = i - 256 * 256;
  if (j >= 0 && j < 80 * 256) {
    int o = j >> 8, k = j & 255;
    float v = (o < 40) ? w2l[o * 256 + k] : w2r[(o - 40) * 256 + k];
    W2c[j] = f2bf(v);
  }
}

// ---------------- layer-1 aggregation: A1 = mean-agg(xb) (128-wide, bf16) ----------------
__global__ void k_agg1(const unsigned* __restrict__ xb, const int* __restrict__ row_ptr,
                       const int* __restrict__ csr_src, unsigned* __restrict__ A1) {
  int w = threadIdx.x >> 6, lane = threadIdx.x & 63;
  int node = blockIdx.x * 4 + w;
  if (node >= NN) return;
  int rs = row_ptr[node], re = row_ptr[node + 1];
  float a0 = 0.f, a1 = 0.f;
  for (int e = rs; e < re; e += 8) {
    unsigned v[8];
#pragma unroll
    for (int j = 0; j < 8; ++j) {
      int ej = e + j;
      int idx = csr_src[ej < re ? ej : re - 1];   // wave-uniform clamp
      unsigned t = xb[(size_t)idx * 64 + lane];
      v[j] = (ej < re) ? t : 0u;                  // wave-uniform mask
    }
#pragma unroll
    for (int j = 0; j < 8; ++j) { a0 += bflo(v[j]); a1 += bfhi(v[j]); }
  }
  int deg = re - rs;
  float inv = 1.f / (float)(deg > 0 ? deg : 1);
  unsigned pack = ((unsigned)f2bf(a1 * inv) << 16) | f2bf(a0 * inv);
  A1[(size_t)node * 64 + lane] = pack;
}

// ---------------- fused GEMM1+GEMM2: H tile lives in LDS only ----------------
// block = 256 thr / 4 waves, 64 node-rows.
// phase 1: Htile = relu([A1|xb] @ Wc^T + b1) -> sH (swizzled)
// phase 2: P^T = W2c @ Htile^T  (H as B-operand); Pb bf16 packed, R f32x4 stores
__global__ __launch_bounds__(256) void k_fused(const unsigned short* __restrict__ A1,
                                               const unsigned short* __restrict__ XB,
                                               const unsigned short* __restrict__ Wc,
                                               const float* __restrict__ b1,
                                               const unsigned short* __restrict__ W2c,
                                               unsigned short* __restrict__ Pb,
                                               float* __restrict__ R) {
  __shared__ __align__(16) unsigned short sA[64 * 64];
  __shared__ __align__(16) unsigned short sB[256 * 64];
  __shared__ __align__(16) unsigned short sH[64 * 256];
  int tid = threadIdx.x;
  int w = tid >> 6, lane = tid & 63;
  int brow = blockIdx.x * 64;
  int wr = (w >> 1) * 32, wc = (w & 1) * 128;
  f32x4 acc[2][8] = {};

  // ---- phase 1 ----
  for (int kt = 0; kt < 4; ++kt) {
    const unsigned short* srcA = (kt < 2) ? A1 : XB;
    int kcol = (kt & 1) * 64;
#pragma unroll
    for (int t = 0; t < 2; ++t) {
      int c = t * 256 + tid;            // 512 chunks: 64 rows x 8 groups
      int r = c >> 3, cc = c & 7;
      int scc = cc ^ (r & 7);
      int gr = brow + r; if (gr > NN - 1) gr = NN - 1;
      gload16(srcA + (size_t)gr * 128 + kcol + scc * 8, sA + c * 8);
    }
#pragma unroll
    for (int t = 0; t < 8; ++t) {
      int c = t * 256 + tid;            // 2048 chunks: 256 rows x 8 groups
      int r = c >> 3, cc = c & 7;
      int scc = cc ^ (r & 7);
      gload16(Wc + (size_t)r * 256 + kt * 64 + scc * 8, sB + c * 8);
    }
    __syncthreads();
#pragma unroll
    for (int kg = 0; kg < 2; ++kg) {
      short8 af[2], bfr[8];
#pragma unroll
      for (int m = 0; m < 2; ++m) {
        int row = wr + m * 16 + (lane & 15);
        int cch = (kg * 4 + (lane >> 4)) ^ (row & 7);
        af[m] = *(const short8*)(sA + row * 64 + cch * 8);
      }
#pragma unroll
      for (int n = 0; n < 8; ++n) {
        int row = wc + n * 16 + (lane & 15);
        int cch = (kg * 4 + (lane >> 4)) ^ (row & 7);
        bfr[n] = *(const short8*)(sB + row * 64 + cch * 8);
      }
#pragma unroll
      for (int m = 0; m < 2; ++m)
#pragma unroll
        for (int n = 0; n < 8; ++n)
          acc[m][n] = __builtin_amdgcn_mfma_f32_16x16x32_bf16(af[m], bfr[n], acc[m][n], 0, 0, 0);
    }
    __syncthreads();
  }

  // ---- Htile -> sH (bias + relu, 32-group XOR swizzle per row) ----
  {
    int colbase = wc + (lane & 15);
    int rowb = wr + (lane >> 4) * 4;
#pragma unroll
    for (int n = 0; n < 8; ++n) {
      int col = colbase + n * 16;
      float bias = b1[col];
      int g = col >> 3, off = col & 7;
#pragma unroll
      for (int m = 0; m < 2; ++m) {
        int row0 = rowb + m * 16;
#pragma unroll
        for (int q = 0; q < 4; ++q) {
          int row = row0 + q;
          float v = acc[m][n][q] + bias;
          v = v > 0.f ? v : 0.f;
          sH[row * 256 + ((g ^ (row & 7)) << 3) + off] = f2bf(v);
        }
      }
    }
  }
  __syncthreads();

  // ---- phase 2: P^T = W2c @ H^T ----
  f32x4 a2[5] = {};
  int nrow = w * 16 + (lane & 15);        // node-within-tile for B operand
  for (int kt = 0; kt < 4; ++kt) {
#pragma unroll
    for (int t = 0; t < 3; ++t) {
      int c = t * 256 + tid;              // 640 chunks: 80 rows x 8 groups
      if (c < 640) {
        int r = c >> 3, cc = c & 7;
        int scc = cc ^ (r & 7);
        gload16(W2c + (size_t)r * 256 + kt * 64 + scc * 8, sB + c * 8);
      }
    }
    __syncthreads();
#pragma unroll
    for (int kg = 0; kg < 2; ++kg) {
      int gH = kt * 8 + kg * 4 + (lane >> 4);
      short8 bf1 = *(const short8*)(sH + nrow * 256 + ((gH ^ (nrow & 7)) << 3));
      short8 af[5];
#pragma unroll
      for (int m = 0; m < 5; ++m) {
        int arow = m * 16 + (lane & 15);
        int cch = (kg * 4 + (lane >> 4)) ^ (arow & 7);
        af[m] = *(const short8*)(sB + arow * 64 + cch * 8);
      }
#pragma unroll
      for (int m = 0; m < 5; ++m)
        a2[m] = __builtin_amdgcn_mfma_f32_16x16x32_bf16(af[m], bf1, a2[m], 0, 0, 0);
    }
    __syncthreads();
  }

  // ---- epilogue: lane owns node=col, 4 consecutive classes ----
  int node = brow + nrow;
  if (node < NN) {
#pragma unroll
    for (int m = 0; m < 5; ++m) {
      int c0 = m * 16 + (lane >> 4) * 4;
      f32x4 v = a2[m];
      if (c0 < NC) {
        uint2 pk;
        pk.x = ((unsigned)f2bf(v[1]) << 16) | f2bf(v[0]);
        pk.y = ((unsigned)f2bf(v[3]) << 16) | f2bf(v[2]);
        *(uint2*)(Pb + (size_t)node * 64 + c0) = pk;
      } else {
        if (c0 < 64) *(uint2*)(Pb + (size_t)node * 64 + c0) = make_uint2(0u, 0u);
        *(float4*)(R + (size_t)node * NC + (c0 - NC)) = make_float4(v[0], v[1], v[2], v[3]);
      }
    }
  }
}

// ---------------- final: out = log_softmax(mean-agg(p) + b2 + r) ----------------
__global__ __launch_bounds__(256) void k_final(const unsigned short* __restrict__ Pb,
                                               const float* __restrict__ R,
                                               const int* __restrict__ row_ptr,
                                               const int* __restrict__ csr_src,
                                               const float* __restrict__ b2,
                                               float* __restrict__ out) {
  int w = threadIdx.x >> 6, lane = threadIdx.x & 63;
  int g = lane >> 4, r = lane & 15;
  int node = blockIdx.x * 4 + w;
  if (node >= NN) return;
  int rs = row_ptr[node], re = row_ptr[node + 1];
  float s0 = 0.f, s1 = 0.f, s2 = 0.f, s3 = 0.f;
  int nfull = (re - rs) >> 3;
  int e = rs + g;
  for (int it = 0; it < nfull; ++it, e += 8) {
    int sa = csr_src[e];
    int sb = csr_src[e + 4];
    uint2 va = *(const uint2*)(Pb + (size_t)sa * 64 + r * 4);
    uint2 vb = *(const uint2*)(Pb + (size_t)sb * 64 + r * 4);
    s0 += bflo(va.x) + bflo(vb.x);
    s1 += bfhi(va.x) + bfhi(vb.x);
    s2 += bflo(va.y) + bflo(vb.y);
    s3 += bfhi(va.y) + bfhi(vb.y);
  }
  if (e < re) {
    int sa = csr_src[e];
    uint2 va = *(const uint2*)(Pb + (size_t)sa * 64 + r * 4);
    s0 += bflo(va.x); s1 += bfhi(va.x); s2 += bflo(va.y); s3 += bfhi(va.y);
  }
  e += 4;
  if (e < re) {
    int sa = csr_src[e];
    uint2 va = *(const uint2*)(Pb + (size_t)sa * 64 + r * 4);
    s0 += bflo(va.x); s1 += bfhi(va.x); s2 += bflo(va.y); s3 += bfhi(va.y);
  }
  s0 += __shfl_xor(s0, 16); s0 += __shfl_xor(s0, 32);
  s1 += __shfl_xor(s1, 16); s1 += __shfl_xor(s1, 32);
  s2 += __shfl_xor(s2, 16); s2 += __shfl_xor(s2, 32);
  s3 += __shfl_xor(s3, 16); s3 += __shfl_xor(s3, 32);

  int deg = re - rs;
  float inv = 1.f / (float)(deg > 0 ? deg : 1);
  bool act = r < 10;
  float4 rr = act ? *(const float4*)(R + (size_t)node * NC + r * 4) : make_float4(0, 0, 0, 0);
  float4 bb = act ? *(const float4*)(b2 + r * 4) : make_float4(0, 0, 0, 0);
  float v0 = s0 * inv + rr.x + bb.x;
  float v1 = s1 * inv + rr.y + bb.y;
  float v2 = s2 * inv + rr.z + bb.z;
  float v3 = s3 * inv + rr.w + bb.w;
  float mx = act ? fmaxf(fmaxf(v0, v1), fmaxf(v2, v3)) : -1e30f;
#pragma unroll
  for (int o = 1; o < 16; o <<= 1) mx = fmaxf(mx, __shfl_xor(mx, o));
  float ex = act ? (__expf(v0 - mx) + __expf(v1 - mx) + __expf(v2 - mx) + __expf(v3 - mx)) : 0.f;
#pragma unroll
  for (int o = 1; o < 16; o <<= 1) ex += __shfl_xor(ex, o);
  float ls = mx + __logf(ex);
  if (g == 0 && act) {
    float4 o4 = make_float4(v0 - ls, v1 - ls, v2 - ls, v3 - ls);
    *(float4*)(out + (size_t)node * NC + r * 4) = o4;
  }
}

extern "C" void kernel_launch(void* const* d_in, const int* in_sizes, int n_in,
                              void* d_out, int out_size, void* d_ws, size_t ws_size,
                              hipStream_t stream) {
  const float* x   = (const float*)d_in[0];
  const int*   ei  = (const int*)d_in[1];
  const float* w1l = (const float*)d_in[2];
  const float* b1  = (const float*)d_in[3];
  const float* w1r = (const float*)d_in[4];
  const float* w2l = (const float*)d_in[5];
  const float* b2  = (const float*)d_in[6];
  const float* w2r = (const float*)d_in[7];
  float* out = (float*)d_out;
  const int* src = ei;
  const int* dst = ei + NE;

  char* ws = (char*)d_ws;
  size_t off = 0;
  auto alloc = [&](size_t bytes) -> char* {
    char* p = ws + off;
    off = (off + bytes + 255) & ~(size_t)255;
    return p;
  };
  int* bcnt     = (int*)alloc((size_t)(NBKT + 1) * 4);
  int* boff     = (int*)alloc((size_t)(NBKT + 1) * 4);
  int* bcur     = (int*)alloc((size_t)NBKT * 4);
  int* row_ptr  = (int*)alloc((size_t)(NN + 1) * 4);
  unsigned* pairs = (unsigned*)alloc((size_t)NE * 4);
  int* csr      = (int*)alloc((size_t)NE * 4);
  unsigned short* Wc  = (unsigned short*)alloc(256 * 256 * 2);
  unsigned short* W2c = (unsigned short*)alloc(80 * 256 * 2);
  unsigned*       xb  = (unsigned*)alloc((size_t)NN * 64 * 4);
  unsigned*       A1  = (unsigned*)alloc((size_t)NN * 64 * 4);   // agg only, 128 bf16/row
  unsigned short* Pb  = (unsigned short*)alloc((size_t)NN * 64 * 2);   // padded to 64 classes
  float*          R   = (float*)alloc((size_t)NN * NC * 4);

  hipMemsetAsync(bcnt, 0, (size_t)(NBKT + 1) * 4, stream);
  k_bhist<<<NBIN_BLOCKS, 256, 0, stream>>>(dst, bcnt);
  k_xbf16<<<(NN * 64 + 255) / 256, 256, 0, stream>>>(x, xb);
  k_bscan<<<1, 512, 0, stream>>>(bcnt, boff, bcur);
  k_bin<<<NBIN_BLOCKS, 256, 0, stream>>>(src, dst, bcur, pairs);
  k_csr<<<NBKT, 256, 0, stream>>>(pairs, boff, row_ptr, csr);
  k_packw<<<336, 256, 0, stream>>>(w1l, w1r, w2l, w2r, Wc, W2c);
  k_agg1<<<(NN + 3) / 4, 256, 0, stream>>>(xb, row_ptr, csr, A1);
  k_fused<<<(NN + 63) / 64, 256, 0, stream>>>((const unsigned short*)A1,
                                              (const unsigned short*)xb, Wc, b1, W2c, Pb, R);
  k_final<<<(NN + 3) / 4, 256, 0, stream>>>(Pb, R, row_ptr, csr, b2, out);
}